// Round 13
// baseline (411.273 us; speedup 1.0000x reference)
//
#include <hip/hip_runtime.h>

typedef unsigned short u16;
typedef unsigned int u32;
typedef __attribute__((ext_vector_type(4))) float f32x4;
typedef __attribute__((ext_vector_type(8))) short short8;
typedef __attribute__((ext_vector_type(4))) u32 u32x4;
typedef __attribute__((ext_vector_type(4))) u16 u16x4;

#define BB 4
#define LL 2048
#define DD 1024
#define HH 8
#define DHH 128

__device__ __forceinline__ u16 f2b(float f) {
  u32 u = __builtin_bit_cast(u32, f);
  u += 0x7fffu + ((u >> 16) & 1u);
  return (u16)(u >> 16);
}
__device__ __forceinline__ float b2f(u16 h) {
  u32 u = ((u32)h) << 16;
  return __builtin_bit_cast(float, u);
}
__device__ __forceinline__ float exp2_fast(float x) {
  float r;
  asm("v_exp_f32 %0, %1" : "=v"(r) : "v"(x));
  return r;
}
__device__ __forceinline__ u32 packbf(float a, float b) {
  return (u32)f2b(a) | ((u32)f2b(b) << 16);
}
__device__ __forceinline__ u32 bperm(int srcLane, u32 v) {
  return (u32)__builtin_amdgcn_ds_bpermute(srcLane << 2, (int)v);
}

#define GLDS16(g, l)                                                          \
  __builtin_amdgcn_global_load_lds(                                           \
      (const __attribute__((address_space(1))) void*)(g),                     \
      (__attribute__((address_space(3))) void*)(l), 16, 0, 0)

#define MFMA_BF16 __builtin_amdgcn_mfma_f32_16x16x32_bf16

// ---------------- elementwise fp32 -> bf16 ----------------
__global__ __launch_bounds__(256) void cvt_k(const float* __restrict__ X,
                                             u16* __restrict__ Xb, long n) {
  long i = ((long)blockIdx.x * 256 + threadIdx.x) * 4;
  if (i >= n) return;
  f32x4 v = *(const f32x4*)(X + i);
  u16x4 o;
#pragma unroll
  for (int k = 0; k < 4; k++) o[k] = f2b(v[k]);
  *(u16x4*)(Xb + i) = o;
}

// ---------------- 1024x1024 fp32 -> bf16 transpose (WT[n][k] = W[k][n]) ----
__global__ __launch_bounds__(256) void tr_k(const float* __restrict__ W,
                                            u16* __restrict__ WT) {
  __shared__ float tile[32][33];
  const int bx = blockIdx.x, by = blockIdx.y;
  const int tx = threadIdx.x & 31, ty = threadIdx.x >> 5;
#pragma unroll
  for (int i = 0; i < 4; i++)
    tile[ty + i * 8][tx] =
        W[(long)(by * 32 + ty + i * 8) * 1024 + bx * 32 + tx];
  __syncthreads();
#pragma unroll
  for (int i = 0; i < 4; i++)
    WT[(long)(bx * 32 + ty + i * 8) * 1024 + by * 32 + tx] =
        f2b(tile[tx][ty + i * 8]);
}

// ============ 8-phase 256x256xK64 GEMM core (m201 template port) ==========
// 8 waves (2M x 4N), per-wave 128x64 output = acc[8][4]. 128KB LDS dbuf.
// Per K-tile: 4 phases, each {ds_read A-quadrant (+B at p0) | stage 1
// half-tile of next K-tile | s_barrier | lgkmcnt(0)+sched_barrier | setprio
// | 16 MFMA | setprio | [p3: vmcnt(0)] | s_barrier}. Raw barriers (no
// implicit vmcnt drain) keep prefetch in flight across phases; per-wave
// vmcnt(0) before the tile-boundary barrier makes cross-wave staging safe.
// LDS layout [256][64] bf16 rows with per-row 16B-unit XOR swizzle applied
// on the gload_lds GLOBAL source and identically on reads (m173 pattern).
__device__ __forceinline__ void g8_loop(const u16* __restrict__ A,
                                        const u16* __restrict__ BT, long bm,
                                        long bnr, u16* AsB, u16* BsB,
                                        f32x4 (&acc)[8][4]) {
  const int t = threadIdx.x;
  const int l = t & 63, w = t >> 6;
  const int lr = l & 15, lg = l >> 4;
  const int wr2 = (w >> 2) * 128, wc2 = (w & 3) * 64;
  const int rA = t >> 3;                 // staging row-within-64 (8 lanes/row)
  const int swz = (t & 7) ^ (rA & 7);    // producer-side XOR (16B units)
  const u16* gA = A + (bm + rA) * 1024 + swz * 8;
  const u16* gB = BT + (bnr + rA) * 1024 + swz * 8;
  u16* const dA = AsB + w * 512;  // wave-uniform base (+h*64rows later)
  u16* const dB = BsB + w * 512;
  int xk[2];
  xk[0] = ((lg) ^ (lr & 7)) * 8;
  xk[1] = ((4 + lg) ^ (lr & 7)) * 8;

  // stage half h (0=A rows0-127, 1=A rows128-255, 2=B0, 3=B1) of tile kt
  auto STG = [&](int h, int nb, int kt) {
    const u16* g = (h < 2) ? gA : gB;
    u16* d = ((h < 2) ? dA : dB) + nb * 16384;
    const int rb = (h & 1) * 128;
    GLDS16(g + (long)rb * 1024 + kt * 64, d + rb * 64);
    GLDS16(g + (long)(rb + 64) * 1024 + kt * 64, d + (rb + 64) * 64);
  };

  // prologue: tile 0 -> buf 0
#pragma unroll
  for (int h = 0; h < 4; h++) STG(h, 0, 0);
  asm volatile("s_waitcnt vmcnt(0)" ::: "memory");
  __builtin_amdgcn_s_barrier();

  short8 bf[4][2];
  for (int kt = 0; kt < 16; ++kt) {
    const int cur = kt & 1;
    const u16* Ac = AsB + cur * 16384;
    const u16* Bc = BsB + cur * 16384;
#pragma unroll
    for (int p = 0; p < 4; ++p) {
      short8 af[2][2];
#pragma unroll
      for (int iq = 0; iq < 2; ++iq) {
        const int arow = wr2 + (p * 2 + iq) * 16 + lr;
#pragma unroll
        for (int ks = 0; ks < 2; ks++)
          af[iq][ks] = *(const short8*)&Ac[arow * 64 + xk[ks]];
      }
      if (p == 0) {
#pragma unroll
        for (int j = 0; j < 4; j++) {
          const int brow = wc2 + j * 16 + lr;
#pragma unroll
          for (int ks = 0; ks < 2; ks++)
            bf[j][ks] = *(const short8*)&Bc[brow * 64 + xk[ks]];
        }
      }
      if (kt + 1 < 16) STG(p, cur ^ 1, kt + 1);
      __builtin_amdgcn_s_barrier();
      asm volatile("s_waitcnt lgkmcnt(0)" ::: "memory");
      __builtin_amdgcn_sched_barrier(0);
      __builtin_amdgcn_s_setprio(1);
#pragma unroll
      for (int iq = 0; iq < 2; ++iq) {
        const int i = p * 2 + iq;
#pragma unroll
        for (int j = 0; j < 4; j++) {
          acc[i][j] = MFMA_BF16(af[iq][0], bf[j][0], acc[i][j], 0, 0, 0);
          acc[i][j] = MFMA_BF16(af[iq][1], bf[j][1], acc[i][j], 0, 0, 0);
        }
      }
      __builtin_amdgcn_s_setprio(0);
      if (p == 3) asm volatile("s_waitcnt vmcnt(0)" ::: "memory");
      __builtin_amdgcn_s_barrier();
    }
  }
}

// ------- fused QKV, 8-phase 256² core: grid (12,32); sector = bxi>>2 -------
__global__ __launch_bounds__(512, 2) void qkv8_k(
    const u16* __restrict__ A, const u16* __restrict__ QT,
    const u16* __restrict__ KT, const u16* __restrict__ VTw,
    const float* __restrict__ bq, const float* __restrict__ bk,
    const float* __restrict__ bv, float qscale, u16* __restrict__ Qo,
    u16* __restrict__ Ko, u16* __restrict__ Vo) {
  __shared__ u16 As[2 * 16384];
  __shared__ u16 Bs[2 * 16384];
  const int nwg = gridDim.x * gridDim.y;  // 384, %8==0
  const int bid = blockIdx.x + blockIdx.y * gridDim.x;
  const int swzb = (bid & 7) * (nwg >> 3) + (bid >> 3);
  const int bxi = swzb % 12, byi = swzb / 12;
  const int sector = bxi >> 2;  // 0=Q 1=K 2=V
  const u16* BT = sector == 0 ? QT : (sector == 1 ? KT : VTw);
  const float* bias = sector == 0 ? bq : (sector == 1 ? bk : bv);
  const float scale = sector == 0 ? qscale : 1.f;
  const long bm = (long)byi * 256;
  const long bnl = (long)(bxi & 3) * 256;  // sector-local col base
  f32x4 acc[8][4] = {};
  g8_loop(A, BT, bm, bnl, As, Bs, acc);

  const int t = threadIdx.x;
  const int l = t & 63, w = t >> 6;
  const int lr = l & 15, lg = l >> 4;
  const int wr2 = (w >> 2) * 128, wc2 = (w & 3) * 64;
#pragma unroll
  for (int i = 0; i < 8; i++)
#pragma unroll
    for (int j = 0; j < 4; j++) {
      long col = bnl + wc2 + j * 16 + lr;
      float bvv = bias[col];
      if (sector == 2) {  // V -> VT layout: VT[(b*1024+col)*2048 + l]
        long row0 = bm + wr2 + i * 16 + lg * 4;
        long b = row0 >> 11, l0 = row0 & 2047;
        u16x4 ov;
#pragma unroll
        for (int r = 0; r < 4; r++) ov[r] = f2b(acc[i][j][r] + bvv);
        *(u16x4*)(Vo + (b * 1024 + col) * 2048 + l0) = ov;
      } else {
        u16* Out = sector == 0 ? Qo : Ko;
#pragma unroll
        for (int r = 0; r < 4; r++) {
          long row = bm + wr2 + i * 16 + lg * 4 + r;
          Out[row * 1024 + col] = f2b((acc[i][j][r] + bvv) * scale);
        }
      }
    }
}

// ------- generic 8-phase 256² GEMM: OMODE 0 = fp32 (+relu), 3 = fused-c2 --
template <bool RELU, int OMODE>
__global__ __launch_bounds__(512, 2) void gemm8_k(
    const u16* __restrict__ A, const u16* __restrict__ BT,
    const float* __restrict__ bias, float* __restrict__ Cf,
    const float* __restrict__ w2, float* __restrict__ cvec) {
  __shared__ u16 As[2 * 16384];
  __shared__ u16 Bs[2 * 16384];
  const int nwg = gridDim.x * gridDim.y;  // 128, %8==0
  const int bid = blockIdx.x + blockIdx.y * gridDim.x;
  const int swzb = (bid & 7) * (nwg >> 3) + (bid >> 3);
  const int bxi = swzb % gridDim.x, byi = swzb / gridDim.x;
  const long bm = (long)byi * 256, bn = (long)bxi * 256;
  f32x4 acc[8][4] = {};
  g8_loop(A, BT, bm, bn, As, Bs, acc);

  const int t = threadIdx.x;
  const int l = t & 63, w = t >> 6;
  const int lr = l & 15, lg = l >> 4;
  const int wr2 = (w >> 2) * 128, wc2 = (w & 3) * 64;
  if (OMODE == 3) {
    float bvj[4], w2j[4];
#pragma unroll
    for (int j = 0; j < 4; j++) {
      long col = bn + wc2 + j * 16 + lr;
      bvj[j] = bias[col];
      w2j[j] = w2[col];
    }
#pragma unroll
    for (int i = 0; i < 8; i++)
#pragma unroll
      for (int r = 0; r < 4; r++) {
        float a2 = 0.f;
#pragma unroll
        for (int j = 0; j < 4; j++)
          a2 += fmaxf(acc[i][j][r] + bvj[j], 0.f) * w2j[j];
        a2 += __shfl_xor(a2, 1, 64);
        a2 += __shfl_xor(a2, 2, 64);
        a2 += __shfl_xor(a2, 4, 64);
        a2 += __shfl_xor(a2, 8, 64);
        if (lr == 0) {
          long row = bm + wr2 + i * 16 + lg * 4 + r;
          atomicAdd(&cvec[row], a2);
        }
      }
  } else {
#pragma unroll
    for (int i = 0; i < 8; i++)
#pragma unroll
      for (int j = 0; j < 4; j++) {
        long col = bn + wc2 + j * 16 + lr;
        float bv = bias[col];
#pragma unroll
        for (int r = 0; r < 4; r++) {
          long row = bm + wr2 + i * 16 + lg * 4 + r;
          float v2 = acc[i][j][r] + bv;
          if (RELU) v2 = fmaxf(v2, 0.f);
          Cf[row * 1024 + col] = v2;
        }
      }
  }
}

// ---------------- flash attention v7 (R12, kept) ---------------------------
__global__ __launch_bounds__(256, 2) void flash_k(const u16* __restrict__ Q,
                                                  const u16* __restrict__ Kb,
                                                  const u16* __restrict__ VT,
                                                  float* __restrict__ ctx) {
  __shared__ u16 Ks2[2][64 * 128];
  __shared__ u16 Vs2[2][128 * 64];
  const int nwg = gridDim.x * gridDim.y;
  const int bid = blockIdx.x + blockIdx.y * gridDim.x;
  const int swz = (bid & 7) * (nwg >> 3) + (bid >> 3);
  const int bxi = swz % gridDim.x, byi = swz / gridDim.x;
  const int t = threadIdx.x;
  const int l = t & 63, w = t >> 6;  // w in 0..3
  const int lr = l & 15, lg = l >> 4;
  const int b = byi >> 3, h = byi & 7;
  const long kbase = ((long)b * LL) * DD + h * DHH;
  const long vtbase = ((long)(b * 8 + h) * DHH) * LL;
  const int q0 = bxi * 128;

  short8 qf0[4], qf1[4];
  {
    const u16* qp0 = Q + kbase + (long)(q0 + w * 32 + lr) * DD + lg * 8;
    const u16* qp1 = qp0 + 16 * DD;
#pragma unroll
    for (int c = 0; c < 4; c++) {
      qf0[c] = *(const short8*)(qp0 + c * 32);
      qf1[c] = *(const short8*)(qp1 + c * 32);
    }
  }
  f32x4 oacc0[8] = {}, oacc1[8] = {};
  float mprev0 = -1e30f, mprev1 = -1e30f;
  float lsum0 = 0.f, lsum1 = 0.f;

  const u16* kg[4];
  const u16* vg[4];
  u16* kl[4];
  u16* vl[4];
#pragma unroll
  for (int i = 0; i < 4; i++) {
    int rk = w * 16 + 4 * i + (l >> 4);
    kg[i] = Kb + kbase + (long)rk * DD + ((l & 15) ^ (rk & 7)) * 8;
    kl[i] = &Ks2[0][(w * 16 + 4 * i) * 128];
    int rv = w * 32 + 8 * i + (l >> 3);
    vg[i] = VT + vtbase + (long)rv * LL + ((l & 7) ^ (rv & 7)) * 8;
    vl[i] = &Vs2[0][(w * 32 + 8 * i) * 64];
  }
#pragma unroll
  for (int i = 0; i < 4; i++) {
    GLDS16(kg[i], kl[i]);
    GLDS16(vg[i], vl[i]);
  }
  __syncthreads();

  int colk[4], colv[2];
#pragma unroll
  for (int c = 0; c < 4; c++) colk[c] = (((c * 4 + lg) ^ (lr & 7)) * 8);
#pragma unroll
  for (int kk = 0; kk < 2; kk++) colv[kk] = (((kk * 4 + lg) ^ (lr & 7)) * 8);

  const int NT = LL / 64;
  for (int it = 0; it < NT; ++it) {
    const int cur = it & 1;
    if (it + 1 < NT) {
      const int ko = (cur ^ 1) * (64 * 128);
      const int vo = (cur ^ 1) * (128 * 64);
#pragma unroll
      for (int i = 0; i < 4; i++) {
        kg[i] += 64 * DD;
        vg[i] += 64;
        GLDS16(kg[i], kl[i] + ko);
        GLDS16(vg[i], vl[i] + vo);
      }
    }
    const u16* Kc = &Ks2[cur][0];
    const u16* Vc = &Vs2[cur][0];

    f32x4 s0[4] = {}, s1[4] = {};
#pragma unroll
    for (int jc = 0; jc < 4; jc++)
#pragma unroll
      for (int c = 0; c < 4; c++) {
        short8 kf = *(const short8*)&Kc[(jc * 16 + lr) * 128 + colk[c]];
        s0[jc] = MFMA_BF16(kf, qf0[c], s0[jc], 0, 0, 0);
        s1[jc] = MFMA_BF16(kf, qf1[c], s1[jc], 0, 0, 0);
      }

    float mx0 = fmaxf(fmaxf(s0[0][0], s0[0][1]), fmaxf(s0[0][2], s0[0][3]));
    float mx1 = fmaxf(fmaxf(s1[0][0], s1[0][1]), fmaxf(s1[0][2], s1[0][3]));
#pragma unroll
    for (int jc = 1; jc < 4; jc++) {
      mx0 = fmaxf(mx0, fmaxf(fmaxf(s0[jc][0], s0[jc][1]),
                             fmaxf(s0[jc][2], s0[jc][3])));
      mx1 = fmaxf(mx1, fmaxf(fmaxf(s1[jc][0], s1[jc][1]),
                             fmaxf(s1[jc][2], s1[jc][3])));
    }
    mx0 = fmaxf(mx0, __shfl_xor(mx0, 16, 64));
    mx0 = fmaxf(mx0, __shfl_xor(mx0, 32, 64));
    mx1 = fmaxf(mx1, __shfl_xor(mx1, 16, 64));
    mx1 = fmaxf(mx1, __shfl_xor(mx1, 32, 64));

    if (__any((int)((mx0 > mprev0 + 8.f) || (mx1 > mprev1 + 8.f)))) {
      float mn0 = fmaxf(mprev0, mx0), mn1 = fmaxf(mprev1, mx1);
      float al0 = exp2_fast(mprev0 - mn0), al1 = exp2_fast(mprev1 - mn1);
      mprev0 = mn0;
      mprev1 = mn1;
      lsum0 *= al0;
      lsum1 *= al1;
      float ar0[4], ar1[4];
#pragma unroll
      for (int r = 0; r < 4; r++) {
        ar0[r] = __shfl(al0, lg * 4 + r, 64);
        ar1[r] = __shfl(al1, lg * 4 + r, 64);
      }
#pragma unroll
      for (int d8 = 0; d8 < 8; d8++)
#pragma unroll
        for (int r = 0; r < 4; r++) {
          oacc0[d8][r] *= ar0[r];
          oacc1[d8][r] *= ar1[r];
        }
    }

    u32 pk0[4][2], pk1[4][2];
    float la0 = 0.f, la1 = 0.f;
#pragma unroll
    for (int jc = 0; jc < 4; jc++) {
      float a0 = exp2_fast(s0[jc][0] - mprev0);
      float a1 = exp2_fast(s0[jc][1] - mprev0);
      float a2 = exp2_fast(s0[jc][2] - mprev0);
      float a3 = exp2_fast(s0[jc][3] - mprev0);
      la0 += (a0 + a1) + (a2 + a3);
      pk0[jc][0] = packbf(a0, a1);
      pk0[jc][1] = packbf(a2, a3);
      float b0 = exp2_fast(s1[jc][0] - mprev1);
      float b1 = exp2_fast(s1[jc][1] - mprev1);
      float b2 = exp2_fast(s1[jc][2] - mprev1);
      float b3 = exp2_fast(s1[jc][3] - mprev1);
      la1 += (b0 + b1) + (b2 + b3);
      pk1[jc][0] = packbf(b0, b1);
      pk1[jc][1] = packbf(b2, b3);
    }
    lsum0 += la0;
    lsum1 += la1;

    short8 pf0[2], pf1[2];
#pragma unroll
    for (int kk = 0; kk < 2; kk++) {
      u32x4 av0, av1;
#pragma unroll
      for (int m = 0; m < 4; m++) {
        int srcl = lr + ((((lg & 1) << 1) + (m >> 1)) << 4);
        u32 x0 = bperm(srcl, pk0[2 * kk][m & 1]);
        u32 x1 = bperm(srcl, pk0[2 * kk + 1][m & 1]);
        av0[m] = (lg >> 1) ? x1 : x0;
        u32 y0 = bperm(srcl, pk1[2 * kk][m & 1]);
        u32 y1 = bperm(srcl, pk1[2 * kk + 1][m & 1]);
        av1[m] = (lg >> 1) ? y1 : y0;
      }
      pf0[kk] = __builtin_bit_cast(short8, av0);
      pf1[kk] = __builtin_bit_cast(short8, av1);
    }

#pragma unroll
    for (int kk = 0; kk < 2; kk++)
#pragma unroll
      for (int d8 = 0; d8 < 8; d8++) {
        short8 vf = *(const short8*)&Vc[(d8 * 16 + lr) * 64 + colv[kk]];
        oacc0[d8] = MFMA_BF16(pf0[kk], vf, oacc0[d8], 0, 0, 0);
        oacc1[d8] = MFMA_BF16(pf1[kk], vf, oacc1[d8], 0, 0, 0);
      }
    __syncthreads();
  }

  lsum0 += __shfl_xor(lsum0, 16, 64);
  lsum0 += __shfl_xor(lsum0, 32, 64);
  lsum1 += __shfl_xor(lsum1, 16, 64);
  lsum1 += __shfl_xor(lsum1, 32, 64);
#pragma unroll
  for (int r = 0; r < 4; r++) {
    float inv0 = 1.f / __shfl(lsum0, lg * 4 + r, 64);
    float inv1 = 1.f / __shfl(lsum1, lg * 4 + r, 64);
    float* cp0 = ctx + kbase + (long)(q0 + w * 32 + lg * 4 + r) * DD;
    float* cp1 = cp0 + 16 * DD;
#pragma unroll
    for (int d8 = 0; d8 < 8; d8++) {
      cp0[d8 * 16 + lr] = oacc0[d8][r] * inv0;
      cp1[d8 * 16 + lr] = oacc1[d8][r] * inv1;
    }
  }
}

// ---------------- residual + layernorm; writes fp32 and/or bf16 ----------
__global__ __launch_bounds__(256) void ln_k(const float* __restrict__ X,
                                            const float* __restrict__ R,
                                            const float* __restrict__ gamma,
                                            const float* __restrict__ beta,
                                            float* __restrict__ Hf,
                                            u16* __restrict__ Hb) {
  const int row = blockIdx.x, t = threadIdx.x;
  const long off = (long)row * DD + t * 4;
  f32x4 v = *(const f32x4*)(X + off);
  f32x4 rv = *(const f32x4*)(R + off);
#pragma unroll
  for (int i = 0; i < 4; i++) v[i] += rv[i];
  float s = v[0] + v[1] + v[2] + v[3];
  float q = v[0] * v[0] + v[1] * v[1] + v[2] * v[2] + v[3] * v[3];
#pragma unroll
  for (int m = 32; m >= 1; m >>= 1) {
    s += __shfl_xor(s, m, 64);
    q += __shfl_xor(q, m, 64);
  }
  __shared__ float red[8];
  if ((t & 63) == 0) {
    red[t >> 6] = s;
    red[4 + (t >> 6)] = q;
  }
  __syncthreads();
  s = red[0] + red[1] + red[2] + red[3];
  q = red[4] + red[5] + red[6] + red[7];
  const float mean = s * (1.f / 1024.f);
  const float var = q * (1.f / 1024.f) - mean * mean;
  const float rstd = rsqrtf(var + 1e-12f);
  f32x4 g = *(const f32x4*)(gamma + t * 4);
  f32x4 be = *(const f32x4*)(beta + t * 4);
  f32x4 o;
#pragma unroll
  for (int i = 0; i < 4; i++) o[i] = g[i] * (v[i] - mean) * rstd + be[i];
  if (Hf) *(f32x4*)(Hf + off) = o;
  if (Hb) {
    u16x4 ob;
#pragma unroll
    for (int i = 0; i < 4; i++) ob[i] = f2b(o[i]);
    *(u16x4*)(Hb + off) = ob;
  }
}

// ---------------- small [4,Lr]@[Lr,N] GEMM: split-K partials + reduce -----
template <bool BR>
__global__ __launch_bounds__(256) void smm_part(const float* __restrict__ Cin,
                                                const float* __restrict__ W,
                                                float* __restrict__ P, int Lr,
                                                int N, int SL,
                                                const float* __restrict__ b0) {
  const int j = blockIdx.x * 256 + threadIdx.x;
  const int l0 = blockIdx.y * SL;
  const float bb = BR ? b0[0] : 0.f;
  float a0 = 0, a1 = 0, a2 = 0, a3 = 0;
  for (int ll = l0; ll < l0 + SL; ll++) {
    float wv = W[(long)ll * N + j];
    float c0 = Cin[ll], c1 = Cin[Lr + ll], c2 = Cin[2 * Lr + ll],
          c3 = Cin[3 * Lr + ll];
    if (BR) {
      c0 = fmaxf(c0 + bb, 0.f);
      c1 = fmaxf(c1 + bb, 0.f);
      c2 = fmaxf(c2 + bb, 0.f);
      c3 = fmaxf(c3 + bb, 0.f);
    }
    a0 += c0 * wv;
    a1 += c1 * wv;
    a2 += c2 * wv;
    a3 += c3 * wv;
  }
  float* Pp = P + ((long)blockIdx.y * 4) * N + j;
  Pp[0] = a0;
  Pp[N] = a1;
  Pp[2 * N] = a2;
  Pp[3 * N] = a3;
}

template <bool RELU>
__global__ __launch_bounds__(256) void smm_red(const float* __restrict__ P,
                                               const float* __restrict__ bias,
                                               float* __restrict__ Out, int N,
                                               int S) {
  const int j = blockIdx.x * 256 + threadIdx.x;
#pragma unroll
  for (int b = 0; b < 4; b++) {
    float a = 0;
    for (int s = 0; s < S; s++) a += P[((long)s * 4 + b) * N + j];
    a += bias[j];
    if (RELU) a = fmaxf(a, 0.f);
    Out[(long)b * N + j] = a;
  }
}

extern "C" void kernel_launch(void* const* d_in, const int* in_sizes, int n_in,
                              void* d_out, int out_size, void* d_ws,
                              size_t ws_size, hipStream_t stream) {
  (void)in_sizes; (void)n_in; (void)out_size; (void)ws_size;
  const float* x = (const float*)d_in[0];
  const float* wq = (const float*)d_in[1];
  const float* bq = (const float*)d_in[2];
  const float* wk = (const float*)d_in[3];
  const float* bk = (const float*)d_in[4];
  const float* wv = (const float*)d_in[5];
  const float* bv = (const float*)d_in[6];
  const float* gamma = (const float*)d_in[7];
  const float* beta = (const float*)d_in[8];
  const float* wff = (const float*)d_in[9];
  const float* bff = (const float*)d_in[10];
  const float* wc1 = (const float*)d_in[11];
  const float* bc1 = (const float*)d_in[12];
  const float* wc2 = (const float*)d_in[13];
  const float* bc2 = (const float*)d_in[14];
  const float* wl1 = (const float*)d_in[15];
  const float* bl1 = (const float*)d_in[16];
  const float* wl2 = (const float*)d_in[17];
  const float* bl2 = (const float*)d_in[18];

  char* wsp = (char*)d_ws;
  size_t off = 0;
  auto take = [&](size_t bytes) -> char* {
    char* p = wsp + off;
    off += (bytes + 255) & ~(size_t)255;
    return p;
  };
  u16* xb = (u16*)take((size_t)8192 * 1024 * 2);
  u16* wqT = (u16*)take((size_t)1024 * 1024 * 2);
  u16* wkT = (u16*)take((size_t)1024 * 1024 * 2);
  u16* wvT = (u16*)take((size_t)1024 * 1024 * 2);
  u16* wffT = (u16*)take((size_t)1024 * 1024 * 2);
  u16* wc1T = (u16*)take((size_t)1024 * 1024 * 2);
  u16* qb = (u16*)take((size_t)8192 * 1024 * 2);
  u16* kbuf = (u16*)take((size_t)8192 * 1024 * 2);
  u16* vT = (u16*)take((size_t)8192 * 1024 * 2);
  float* ctxb = (float*)take((size_t)8192 * 1024 * 4);
  float* h1f = (float*)take((size_t)8192 * 1024 * 4);
  float* cvec = (float*)take(8192 * 4);
  float* c3 = (float*)take(8192 * 4);
  float* P1 = (float*)take((size_t)16 * 4 * 2048 * 4);
  float* P2 = (float*)take((size_t)16 * 4 * 256 * 4);
  u16* h1b = qb;
  u16* h2b = kbuf;
  float* ff = ctxb;

  cvt_k<<<8192, 256, 0, stream>>>(x, xb, (long)8192 * 1024);
  dim3 trg(32, 32);
  tr_k<<<trg, 256, 0, stream>>>(wq, wqT);
  tr_k<<<trg, 256, 0, stream>>>(wk, wkT);
  tr_k<<<trg, 256, 0, stream>>>(wv, wvT);
  tr_k<<<trg, 256, 0, stream>>>(wff, wffT);
  tr_k<<<trg, 256, 0, stream>>>(wc1, wc1T);

  // fused QKV, 8-phase 256² core; Q scale folds 1/sqrt(128)*log2(e)
  qkv8_k<<<dim3(12, 32), 512, 0, stream>>>(xb, wqT, wkT, wvT, bq, bk, bv,
                                           0.12751743f, qb, kbuf, vT);
  flash_k<<<dim3(16, 32), 256, 0, stream>>>(qb, kbuf, vT, ctxb);
  ln_k<<<8192, 256, 0, stream>>>(x, ctxb, gamma, beta, h1f, h1b);
  gemm8_k<true, 0><<<dim3(4, 32), 512, 0, stream>>>(h1b, wffT, bff, ff,
                                                    nullptr, nullptr);
  ln_k<<<8192, 256, 0, stream>>>(h1f, ff, gamma, beta, nullptr, h2b);
  hipMemsetAsync(cvec, 0, 8192 * sizeof(float), stream);
  gemm8_k<true, 3><<<dim3(4, 32), 512, 0, stream>>>(h2b, wc1T, bc1, nullptr,
                                                    wc2, cvec);
  smm_part<true><<<dim3(8, 16), 256, 0, stream>>>(cvec, wl1, P1, 2048, 2048,
                                                  128, bc2);
  smm_red<true><<<8, 256, 0, stream>>>(P1, bl1, c3, 2048, 16);
  smm_part<false><<<dim3(1, 16), 256, 0, stream>>>(c3, wl2, P2, 2048, 256,
                                                   128, nullptr);
  smm_red<false><<<1, 256, 0, stream>>>(P2, bl2, (float*)d_out, 256, 16);
}

// Round 14
// 372.353 us; speedup vs baseline: 1.1045x; 1.1045x over previous
//
#include <hip/hip_runtime.h>

typedef unsigned short u16;
typedef unsigned int u32;
typedef __attribute__((ext_vector_type(4))) float f32x4;
typedef __attribute__((ext_vector_type(8))) short short8;
typedef __attribute__((ext_vector_type(4))) u32 u32x4;
typedef __attribute__((ext_vector_type(4))) u16 u16x4;

#define BB 4
#define LL 2048
#define DD 1024
#define HH 8
#define DHH 128

__device__ __forceinline__ u16 f2b(float f) {
  u32 u = __builtin_bit_cast(u32, f);
  u += 0x7fffu + ((u >> 16) & 1u);
  return (u16)(u >> 16);
}
__device__ __forceinline__ float b2f(u16 h) {
  u32 u = ((u32)h) << 16;
  return __builtin_bit_cast(float, u);
}
// raw v_exp_f32: D = 2^S0 (ISA §3) — exp2 with no mul
__device__ __forceinline__ float exp2_fast(float x) {
  float r;
  asm("v_exp_f32 %0, %1" : "=v"(r) : "v"(x));
  return r;
}
__device__ __forceinline__ u32 packbf(float a, float b) {
  return (u32)f2b(a) | ((u32)f2b(b) << 16);
}
__device__ __forceinline__ u32 bperm(int srcLane, u32 v) {
  return (u32)__builtin_amdgcn_ds_bpermute(srcLane << 2, (int)v);
}

#define GLDS16(g, l)                                                          \
  __builtin_amdgcn_global_load_lds(                                           \
      (const __attribute__((address_space(1))) void*)(g),                     \
      (__attribute__((address_space(3))) void*)(l), 16, 0, 0)

#define MFMA_BF16 __builtin_amdgcn_mfma_f32_16x16x32_bf16

// ---------------- elementwise fp32 -> bf16 ----------------
__global__ __launch_bounds__(256) void cvt_k(const float* __restrict__ X,
                                             u16* __restrict__ Xb, long n) {
  long i = ((long)blockIdx.x * 256 + threadIdx.x) * 4;
  if (i >= n) return;
  f32x4 v = *(const f32x4*)(X + i);
  u16x4 o;
#pragma unroll
  for (int k = 0; k < 4; k++) o[k] = f2b(v[k]);
  *(u16x4*)(Xb + i) = o;
}

// ---------------- 1024x1024 fp32 -> bf16 transpose (WT[n][k] = W[k][n]) ----
__global__ __launch_bounds__(256) void tr_k(const float* __restrict__ W,
                                            u16* __restrict__ WT) {
  __shared__ float tile[32][33];
  const int bx = blockIdx.x, by = blockIdx.y;
  const int tx = threadIdx.x & 31, ty = threadIdx.x >> 5;
#pragma unroll
  for (int i = 0; i < 4; i++)
    tile[ty + i * 8][tx] =
        W[(long)(by * 32 + ty + i * 8) * 1024 + bx * 32 + tx];
  __syncthreads();
#pragma unroll
  for (int i = 0; i < 4; i++)
    WT[(long)(bx * 32 + ty + i * 8) * 1024 + by * 32 + tx] =
        f2b(tile[tx][ty + i * 8]);
}

// ------- fused QKV GEMM: grid (24,64); sector = bxi>>3 in {Q,K,V} ---------
__global__ __launch_bounds__(256, 3) void qkv_k(
    const u16* __restrict__ A, const u16* __restrict__ QT,
    const u16* __restrict__ KT, const u16* __restrict__ VTw,
    const float* __restrict__ bq, const float* __restrict__ bk,
    const float* __restrict__ bv, float qscale, u16* __restrict__ Qo,
    u16* __restrict__ Ko, u16* __restrict__ Vo) {
  __shared__ u16 As[2][128 * 32];
  __shared__ u16 Bs[2][128 * 32];
  const int K = 1024;
  const int nwg = gridDim.x * gridDim.y;  // 1536, %8==0
  const int bid = blockIdx.x + blockIdx.y * gridDim.x;
  const int swz = (bid & 7) * (nwg >> 3) + (bid >> 3);
  const int bxi = swz % 24, byi = swz / 24;
  const int sector = bxi >> 3;  // 0=Q 1=K 2=V
  const u16* BT = sector == 0 ? QT : (sector == 1 ? KT : VTw);
  const float* bias = sector == 0 ? bq : (sector == 1 ? bk : bv);
  const float scale = sector == 0 ? qscale : 1.f;
  const int t = threadIdx.x;
  const int l = t & 63, w = t >> 6;
  const int lr = l & 15, lg = l >> 4;
  const int wr = (w >> 1) * 64, wc = (w & 1) * 64;
  const long bm = (long)byi * 128, bn = (long)(bxi & 7) * 128;
  const int srow = l >> 2;
  const int scol = (l & 3) * 8;
  const u16* Ag0 = A + (bm + w * 32 + srow) * (long)K + scol;
  const u16* Ag1 = A + (bm + w * 32 + 16 + srow) * (long)K + scol;
  const u16* Bg0 = BT + (bn + w * 32 + srow) * (long)K + scol;
  const u16* Bg1 = BT + (bn + w * 32 + 16 + srow) * (long)K + scol;
  const int wo = w * 1024;
  f32x4 acc[4][4] = {};
  GLDS16(Ag0, &As[0][wo]);
  GLDS16(Ag1, &As[0][wo + 512]);
  GLDS16(Bg0, &Bs[0][wo]);
  GLDS16(Bg1, &Bs[0][wo + 512]);
  __syncthreads();
  int cur = 0;
  for (int k0 = 0; k0 < K; k0 += 32) {
    const int nxt = cur ^ 1;
    if (k0 + 32 < K) {
      GLDS16(Ag0 + k0 + 32, &As[nxt][wo]);
      GLDS16(Ag1 + k0 + 32, &As[nxt][wo + 512]);
      GLDS16(Bg0 + k0 + 32, &Bs[nxt][wo]);
      GLDS16(Bg1 + k0 + 32, &Bs[nxt][wo + 512]);
    }
    short8 af[4], bf[4];
#pragma unroll
    for (int i = 0; i < 4; i++)
      af[i] = *(const short8*)&As[cur][(wr + i * 16 + lr) * 32 + lg * 8];
#pragma unroll
    for (int i = 0; i < 4; i++)
      bf[i] = *(const short8*)&Bs[cur][(wc + i * 16 + lr) * 32 + lg * 8];
#pragma unroll
    for (int i = 0; i < 4; i++)
#pragma unroll
      for (int j = 0; j < 4; j++)
        acc[i][j] = MFMA_BF16(af[i], bf[j], acc[i][j], 0, 0, 0);
    __syncthreads();
    cur = nxt;
  }
#pragma unroll
  for (int i = 0; i < 4; i++)
#pragma unroll
    for (int j = 0; j < 4; j++) {
      long col = bn + wc + j * 16 + lr;
      float bvv = bias[col];
      if (sector == 2) {  // V -> VT layout: VT[(b*1024+col)*2048 + l]
        long row0 = bm + wr + i * 16 + lg * 4;
        long b = row0 >> 11, l0 = row0 & 2047;
        u16x4 ov;
#pragma unroll
        for (int r = 0; r < 4; r++) ov[r] = f2b(acc[i][j][r] + bvv);
        *(u16x4*)(Vo + (b * 1024 + col) * 2048 + l0) = ov;
      } else {
        u16* Out = sector == 0 ? Qo : Ko;
#pragma unroll
        for (int r = 0; r < 4; r++) {
          long row = bm + wr + i * 16 + lg * 4 + r;
          Out[row * 1024 + col] = f2b((acc[i][j][r] + bvv) * scale);
        }
      }
    }
}

// ------- generic 128x128x32 GEMM, 2-phase dbuf ----------------------------
// OMODE: 0 = fp32 row-major (+relu opt); 3 = fused-c2.
template <bool RELU, int OMODE>
__global__ __launch_bounds__(256, 3) void gemm_k(
    const u16* __restrict__ A, const u16* __restrict__ BT,
    const float* __restrict__ bias, float scale, float* __restrict__ Cf,
    u16* __restrict__ Cb, const float* __restrict__ w2,
    float* __restrict__ cvec, int M, int N, int K) {
  __shared__ u16 As[2][128 * 32];
  __shared__ u16 Bs[2][128 * 32];
  const int nwg = gridDim.x * gridDim.y;
  const int bid = blockIdx.x + blockIdx.y * gridDim.x;
  const int swz = (bid & 7) * (nwg >> 3) + (bid >> 3);
  const int bxi = swz % gridDim.x, byi = swz / gridDim.x;
  const int t = threadIdx.x;
  const int l = t & 63, w = t >> 6;
  const int lr = l & 15, lg = l >> 4;
  const int wr = (w >> 1) * 64, wc = (w & 1) * 64;
  const long bm = (long)byi * 128, bn = (long)bxi * 128;
  const int srow = l >> 2;
  const int scol = (l & 3) * 8;
  const u16* Ag0 = A + (bm + w * 32 + srow) * (long)K + scol;
  const u16* Ag1 = A + (bm + w * 32 + 16 + srow) * (long)K + scol;
  const u16* Bg0 = BT + (bn + w * 32 + srow) * (long)K + scol;
  const u16* Bg1 = BT + (bn + w * 32 + 16 + srow) * (long)K + scol;
  const int wo = w * 1024;
  f32x4 acc[4][4] = {};
  GLDS16(Ag0, &As[0][wo]);
  GLDS16(Ag1, &As[0][wo + 512]);
  GLDS16(Bg0, &Bs[0][wo]);
  GLDS16(Bg1, &Bs[0][wo + 512]);
  __syncthreads();
  int cur = 0;
  for (int k0 = 0; k0 < K; k0 += 32) {
    const int nxt = cur ^ 1;
    if (k0 + 32 < K) {
      GLDS16(Ag0 + k0 + 32, &As[nxt][wo]);
      GLDS16(Ag1 + k0 + 32, &As[nxt][wo + 512]);
      GLDS16(Bg0 + k0 + 32, &Bs[nxt][wo]);
      GLDS16(Bg1 + k0 + 32, &Bs[nxt][wo + 512]);
    }
    short8 af[4], bf[4];
#pragma unroll
    for (int i = 0; i < 4; i++)
      af[i] = *(const short8*)&As[cur][(wr + i * 16 + lr) * 32 + lg * 8];
#pragma unroll
    for (int i = 0; i < 4; i++)
      bf[i] = *(const short8*)&Bs[cur][(wc + i * 16 + lr) * 32 + lg * 8];
#pragma unroll
    for (int i = 0; i < 4; i++)
#pragma unroll
      for (int j = 0; j < 4; j++)
        acc[i][j] = MFMA_BF16(af[i], bf[j], acc[i][j], 0, 0, 0);
    __syncthreads();
    cur = nxt;
  }
  if (OMODE == 3) {
    float bvj[4], w2j[4];
#pragma unroll
    for (int j = 0; j < 4; j++) {
      long col = bn + wc + j * 16 + lr;
      bvj[j] = bias[col];
      w2j[j] = w2[col];
    }
#pragma unroll
    for (int i = 0; i < 4; i++)
#pragma unroll
      for (int r = 0; r < 4; r++) {
        float a2 = 0.f;
#pragma unroll
        for (int j = 0; j < 4; j++)
          a2 += fmaxf(acc[i][j][r] + bvj[j], 0.f) * w2j[j];
        a2 += __shfl_xor(a2, 1, 64);
        a2 += __shfl_xor(a2, 2, 64);
        a2 += __shfl_xor(a2, 4, 64);
        a2 += __shfl_xor(a2, 8, 64);
        if (lr == 0) {
          long row = bm + wr + i * 16 + lg * 4 + r;
          atomicAdd(&cvec[row], a2);
        }
      }
  } else {
#pragma unroll
    for (int i = 0; i < 4; i++)
#pragma unroll
      for (int j = 0; j < 4; j++) {
        long col = bn + wc + j * 16 + lr;
        float bv = bias[col];
#pragma unroll
        for (int r = 0; r < 4; r++) {
          long row = bm + wr + i * 16 + lg * 4 + r;
          float v2 = (acc[i][j][r] + bv) * scale;
          if (RELU) v2 = fmaxf(v2, 0.f);
          Cf[row * N + col] = v2;
        }
      }
  }
}

// ---------------- flash attention v7: 4 waves x 32 q-rows (R12, kept) ------
__global__ __launch_bounds__(256, 2) void flash_k(const u16* __restrict__ Q,
                                                  const u16* __restrict__ Kb,
                                                  const u16* __restrict__ VT,
                                                  float* __restrict__ ctx) {
  __shared__ u16 Ks2[2][64 * 128];
  __shared__ u16 Vs2[2][128 * 64];
  const int nwg = gridDim.x * gridDim.y;
  const int bid = blockIdx.x + blockIdx.y * gridDim.x;
  const int swz = (bid & 7) * (nwg >> 3) + (bid >> 3);
  const int bxi = swz % gridDim.x, byi = swz / gridDim.x;
  const int t = threadIdx.x;
  const int l = t & 63, w = t >> 6;  // w in 0..3
  const int lr = l & 15, lg = l >> 4;
  const int b = byi >> 3, h = byi & 7;
  const long kbase = ((long)b * LL) * DD + h * DHH;
  const long vtbase = ((long)(b * 8 + h) * DHH) * LL;
  const int q0 = bxi * 128;

  short8 qf0[4], qf1[4];
  {
    const u16* qp0 = Q + kbase + (long)(q0 + w * 32 + lr) * DD + lg * 8;
    const u16* qp1 = qp0 + 16 * DD;
#pragma unroll
    for (int c = 0; c < 4; c++) {
      qf0[c] = *(const short8*)(qp0 + c * 32);
      qf1[c] = *(const short8*)(qp1 + c * 32);
    }
  }
  f32x4 oacc0[8] = {}, oacc1[8] = {};
  float mprev0 = -1e30f, mprev1 = -1e30f;
  float lsum0 = 0.f, lsum1 = 0.f;

  const u16* kg[4];
  const u16* vg[4];
  u16* kl[4];
  u16* vl[4];
#pragma unroll
  for (int i = 0; i < 4; i++) {
    int rk = w * 16 + 4 * i + (l >> 4);
    kg[i] = Kb + kbase + (long)rk * DD + ((l & 15) ^ (rk & 7)) * 8;
    kl[i] = &Ks2[0][(w * 16 + 4 * i) * 128];
    int rv = w * 32 + 8 * i + (l >> 3);
    vg[i] = VT + vtbase + (long)rv * LL + ((l & 7) ^ (rv & 7)) * 8;
    vl[i] = &Vs2[0][(w * 32 + 8 * i) * 64];
  }
#pragma unroll
  for (int i = 0; i < 4; i++) {
    GLDS16(kg[i], kl[i]);
    GLDS16(vg[i], vl[i]);
  }
  __syncthreads();

  int colk[4], colv[2];
#pragma unroll
  for (int c = 0; c < 4; c++) colk[c] = (((c * 4 + lg) ^ (lr & 7)) * 8);
#pragma unroll
  for (int kk = 0; kk < 2; kk++) colv[kk] = (((kk * 4 + lg) ^ (lr & 7)) * 8);

  const int NT = LL / 64;
  for (int it = 0; it < NT; ++it) {
    const int cur = it & 1;
    if (it + 1 < NT) {
      const int ko = (cur ^ 1) * (64 * 128);
      const int vo = (cur ^ 1) * (128 * 64);
#pragma unroll
      for (int i = 0; i < 4; i++) {
        kg[i] += 64 * DD;
        vg[i] += 64;
        GLDS16(kg[i], kl[i] + ko);
        GLDS16(vg[i], vl[i] + vo);
      }
    }
    const u16* Kc = &Ks2[cur][0];
    const u16* Vc = &Vs2[cur][0];

    f32x4 s0[4] = {}, s1[4] = {};
#pragma unroll
    for (int jc = 0; jc < 4; jc++)
#pragma unroll
      for (int c = 0; c < 4; c++) {
        short8 kf = *(const short8*)&Kc[(jc * 16 + lr) * 128 + colk[c]];
        s0[jc] = MFMA_BF16(kf, qf0[c], s0[jc], 0, 0, 0);
        s1[jc] = MFMA_BF16(kf, qf1[c], s1[jc], 0, 0, 0);
      }

    float mx0 = fmaxf(fmaxf(s0[0][0], s0[0][1]), fmaxf(s0[0][2], s0[0][3]));
    float mx1 = fmaxf(fmaxf(s1[0][0], s1[0][1]), fmaxf(s1[0][2], s1[0][3]));
#pragma unroll
    for (int jc = 1; jc < 4; jc++) {
      mx0 = fmaxf(mx0, fmaxf(fmaxf(s0[jc][0], s0[jc][1]),
                             fmaxf(s0[jc][2], s0[jc][3])));
      mx1 = fmaxf(mx1, fmaxf(fmaxf(s1[jc][0], s1[jc][1]),
                             fmaxf(s1[jc][2], s1[jc][3])));
    }
    mx0 = fmaxf(mx0, __shfl_xor(mx0, 16, 64));
    mx0 = fmaxf(mx0, __shfl_xor(mx0, 32, 64));
    mx1 = fmaxf(mx1, __shfl_xor(mx1, 16, 64));
    mx1 = fmaxf(mx1, __shfl_xor(mx1, 32, 64));

    if (__any((int)((mx0 > mprev0 + 8.f) || (mx1 > mprev1 + 8.f)))) {
      float mn0 = fmaxf(mprev0, mx0), mn1 = fmaxf(mprev1, mx1);
      float al0 = exp2_fast(mprev0 - mn0), al1 = exp2_fast(mprev1 - mn1);
      mprev0 = mn0;
      mprev1 = mn1;
      lsum0 *= al0;
      lsum1 *= al1;
      float ar0[4], ar1[4];
#pragma unroll
      for (int r = 0; r < 4; r++) {
        ar0[r] = __shfl(al0, lg * 4 + r, 64);
        ar1[r] = __shfl(al1, lg * 4 + r, 64);
      }
#pragma unroll
      for (int d8 = 0; d8 < 8; d8++)
#pragma unroll
        for (int r = 0; r < 4; r++) {
          oacc0[d8][r] *= ar0[r];
          oacc1[d8][r] *= ar1[r];
        }
    }

    u32 pk0[4][2], pk1[4][2];
    float la0 = 0.f, la1 = 0.f;
#pragma unroll
    for (int jc = 0; jc < 4; jc++) {
      float a0 = exp2_fast(s0[jc][0] - mprev0);
      float a1 = exp2_fast(s0[jc][1] - mprev0);
      float a2 = exp2_fast(s0[jc][2] - mprev0);
      float a3 = exp2_fast(s0[jc][3] - mprev0);
      la0 += (a0 + a1) + (a2 + a3);
      pk0[jc][0] = packbf(a0, a1);
      pk0[jc][1] = packbf(a2, a3);
      float b0 = exp2_fast(s1[jc][0] - mprev1);
      float b1 = exp2_fast(s1[jc][1] - mprev1);
      float b2 = exp2_fast(s1[jc][2] - mprev1);
      float b3 = exp2_fast(s1[jc][3] - mprev1);
      la1 += (b0 + b1) + (b2 + b3);
      pk1[jc][0] = packbf(b0, b1);
      pk1[jc][1] = packbf(b2, b3);
    }
    lsum0 += la0;
    lsum1 += la1;

    short8 pf0[2], pf1[2];
#pragma unroll
    for (int kk = 0; kk < 2; kk++) {
      u32x4 av0, av1;
#pragma unroll
      for (int m = 0; m < 4; m++) {
        int srcl = lr + ((((lg & 1) << 1) + (m >> 1)) << 4);
        u32 x0 = bperm(srcl, pk0[2 * kk][m & 1]);
        u32 x1 = bperm(srcl, pk0[2 * kk + 1][m & 1]);
        av0[m] = (lg >> 1) ? x1 : x0;
        u32 y0 = bperm(srcl, pk1[2 * kk][m & 1]);
        u32 y1 = bperm(srcl, pk1[2 * kk + 1][m & 1]);
        av1[m] = (lg >> 1) ? y1 : y0;
      }
      pf0[kk] = __builtin_bit_cast(short8, av0);
      pf1[kk] = __builtin_bit_cast(short8, av1);
    }

#pragma unroll
    for (int kk = 0; kk < 2; kk++)
#pragma unroll
      for (int d8 = 0; d8 < 8; d8++) {
        short8 vf = *(const short8*)&Vc[(d8 * 16 + lr) * 64 + colv[kk]];
        oacc0[d8] = MFMA_BF16(pf0[kk], vf, oacc0[d8], 0, 0, 0);
        oacc1[d8] = MFMA_BF16(pf1[kk], vf, oacc1[d8], 0, 0, 0);
      }
    __syncthreads();
  }

  lsum0 += __shfl_xor(lsum0, 16, 64);
  lsum0 += __shfl_xor(lsum0, 32, 64);
  lsum1 += __shfl_xor(lsum1, 16, 64);
  lsum1 += __shfl_xor(lsum1, 32, 64);
#pragma unroll
  for (int r = 0; r < 4; r++) {
    float inv0 = 1.f / __shfl(lsum0, lg * 4 + r, 64);
    float inv1 = 1.f / __shfl(lsum1, lg * 4 + r, 64);
    float* cp0 = ctx + kbase + (long)(q0 + w * 32 + lg * 4 + r) * DD;
    float* cp1 = cp0 + 16 * DD;
#pragma unroll
    for (int d8 = 0; d8 < 8; d8++) {
      cp0[d8 * 16 + lr] = oacc0[d8][r] * inv0;
      cp1[d8 * 16 + lr] = oacc1[d8][r] * inv1;
    }
  }
}

// ---------------- residual + layernorm --------------------------------
// XB: X input is bf16 (residual path h1b) instead of fp32. Writes bf16 out;
// optional fp32 out dropped (LN2 reads h1b, saving the h1f round-trip).
template <bool XB>
__global__ __launch_bounds__(256) void ln_k(const void* __restrict__ Xp,
                                            const float* __restrict__ R,
                                            const float* __restrict__ gamma,
                                            const float* __restrict__ beta,
                                            u16* __restrict__ Hb) {
  const int row = blockIdx.x, t = threadIdx.x;
  const long off = (long)row * DD + t * 4;
  f32x4 v;
  if (XB) {
    u16x4 xv = *(const u16x4*)((const u16*)Xp + off);
#pragma unroll
    for (int i = 0; i < 4; i++) v[i] = b2f(xv[i]);
  } else {
    v = *(const f32x4*)((const float*)Xp + off);
  }
  f32x4 rv = *(const f32x4*)(R + off);
#pragma unroll
  for (int i = 0; i < 4; i++) v[i] += rv[i];
  float s = v[0] + v[1] + v[2] + v[3];
  float q = v[0] * v[0] + v[1] * v[1] + v[2] * v[2] + v[3] * v[3];
#pragma unroll
  for (int m = 32; m >= 1; m >>= 1) {
    s += __shfl_xor(s, m, 64);
    q += __shfl_xor(q, m, 64);
  }
  __shared__ float red[8];
  if ((t & 63) == 0) {
    red[t >> 6] = s;
    red[4 + (t >> 6)] = q;
  }
  __syncthreads();
  s = red[0] + red[1] + red[2] + red[3];
  q = red[4] + red[5] + red[6] + red[7];
  const float mean = s * (1.f / 1024.f);
  const float var = q * (1.f / 1024.f) - mean * mean;
  const float rstd = rsqrtf(var + 1e-12f);
  f32x4 g = *(const f32x4*)(gamma + t * 4);
  f32x4 be = *(const f32x4*)(beta + t * 4);
  u16x4 ob;
#pragma unroll
  for (int i = 0; i < 4; i++)
    ob[i] = f2b(g[i] * (v[i] - mean) * rstd + be[i]);
  *(u16x4*)(Hb + off) = ob;
}

// ---------------- small [4,Lr]@[Lr,N] GEMM: split-K partials + reduce -----
template <bool BR>
__global__ __launch_bounds__(256) void smm_part(const float* __restrict__ Cin,
                                                const float* __restrict__ W,
                                                float* __restrict__ P, int Lr,
                                                int N, int SL,
                                                const float* __restrict__ b0) {
  const int j = blockIdx.x * 256 + threadIdx.x;
  const int l0 = blockIdx.y * SL;
  const float bb = BR ? b0[0] : 0.f;
  float a0 = 0, a1 = 0, a2 = 0, a3 = 0;
  for (int ll = l0; ll < l0 + SL; ll++) {
    float wv = W[(long)ll * N + j];
    float c0 = Cin[ll], c1 = Cin[Lr + ll], c2 = Cin[2 * Lr + ll],
          c3 = Cin[3 * Lr + ll];
    if (BR) {
      c0 = fmaxf(c0 + bb, 0.f);
      c1 = fmaxf(c1 + bb, 0.f);
      c2 = fmaxf(c2 + bb, 0.f);
      c3 = fmaxf(c3 + bb, 0.f);
    }
    a0 += c0 * wv;
    a1 += c1 * wv;
    a2 += c2 * wv;
    a3 += c3 * wv;
  }
  float* Pp = P + ((long)blockIdx.y * 4) * N + j;
  Pp[0] = a0;
  Pp[N] = a1;
  Pp[2 * N] = a2;
  Pp[3 * N] = a3;
}

template <bool RELU>
__global__ __launch_bounds__(256) void smm_red(const float* __restrict__ P,
                                               const float* __restrict__ bias,
                                               float* __restrict__ Out, int N,
                                               int S) {
  const int j = blockIdx.x * 256 + threadIdx.x;
#pragma unroll
  for (int b = 0; b < 4; b++) {
    float a = 0;
    for (int s = 0; s < S; s++) a += P[((long)s * 4 + b) * N + j];
    a += bias[j];
    if (RELU) a = fmaxf(a, 0.f);
    Out[(long)b * N + j] = a;
  }
}

extern "C" void kernel_launch(void* const* d_in, const int* in_sizes, int n_in,
                              void* d_out, int out_size, void* d_ws,
                              size_t ws_size, hipStream_t stream) {
  (void)in_sizes; (void)n_in; (void)out_size; (void)ws_size;
  const float* x = (const float*)d_in[0];
  const float* wq = (const float*)d_in[1];
  const float* bq = (const float*)d_in[2];
  const float* wk = (const float*)d_in[3];
  const float* bk = (const float*)d_in[4];
  const float* wv = (const float*)d_in[5];
  const float* bv = (const float*)d_in[6];
  const float* gamma = (const float*)d_in[7];
  const float* beta = (const float*)d_in[8];
  const float* wff = (const float*)d_in[9];
  const float* bff = (const float*)d_in[10];
  const float* wc1 = (const float*)d_in[11];
  const float* bc1 = (const float*)d_in[12];
  const float* wc2 = (const float*)d_in[13];
  const float* bc2 = (const float*)d_in[14];
  const float* wl1 = (const float*)d_in[15];
  const float* bl1 = (const float*)d_in[16];
  const float* wl2 = (const float*)d_in[17];
  const float* bl2 = (const float*)d_in[18];

  char* wsp = (char*)d_ws;
  size_t off = 0;
  auto take = [&](size_t bytes) -> char* {
    char* p = wsp + off;
    off += (bytes + 255) & ~(size_t)255;
    return p;
  };
  u16* xb = (u16*)take((size_t)8192 * 1024 * 2);
  u16* wqT = (u16*)take((size_t)1024 * 1024 * 2);
  u16* wkT = (u16*)take((size_t)1024 * 1024 * 2);
  u16* wvT = (u16*)take((size_t)1024 * 1024 * 2);
  u16* wffT = (u16*)take((size_t)1024 * 1024 * 2);
  u16* wc1T = (u16*)take((size_t)1024 * 1024 * 2);
  u16* qb = (u16*)take((size_t)8192 * 1024 * 2);
  u16* kbuf = (u16*)take((size_t)8192 * 1024 * 2);
  u16* vT = (u16*)take((size_t)8192 * 1024 * 2);
  float* ctxb = (float*)take((size_t)8192 * 1024 * 4);
  u16* h1b = (u16*)take((size_t)8192 * 1024 * 2);
  float* cvec = (float*)take(8192 * 4);
  float* c3 = (float*)take(8192 * 4);
  float* P1 = (float*)take((size_t)16 * 4 * 2048 * 4);
  float* P2 = (float*)take((size_t)16 * 4 * 256 * 4);
  u16* h2b = qb;     // dead after flash
  float* ff = ctxb;  // in-place over ctx after LN1 reads it? NO — ff GEMM
                     // writes while ctxb... ff must not alias ctxb input.
  // ff GEMM reads h1b, writes ff. ctxb is dead after LN1 -> safe to reuse.

  cvt_k<<<8192, 256, 0, stream>>>(x, xb, (long)8192 * 1024);
  dim3 trg(32, 32);
  tr_k<<<trg, 256, 0, stream>>>(wq, wqT);
  tr_k<<<trg, 256, 0, stream>>>(wk, wkT);
  tr_k<<<trg, 256, 0, stream>>>(wv, wvT);
  tr_k<<<trg, 256, 0, stream>>>(wff, wffT);
  tr_k<<<trg, 256, 0, stream>>>(wc1, wc1T);

  // fused QKV: grid (3*8, 64); Q scale folds 1/sqrt(128)*log2(e)
  qkv_k<<<dim3(24, 64), 256, 0, stream>>>(xb, wqT, wkT, wvT, bq, bk, bv,
                                          0.12751743f, qb, kbuf, vT);
  flash_k<<<dim3(16, 32), 256, 0, stream>>>(qb, kbuf, vT, ctxb);
  // LN1: x (fp32) + ctx -> h1b (bf16 only; h1f round-trip eliminated)
  ln_k<false><<<8192, 256, 0, stream>>>(x, ctxb, gamma, beta, h1b);
  dim3 gg(8, 64);
  gemm_k<true, 0><<<gg, 256, 0, stream>>>(h1b, wffT, bff, 1.f, ff, nullptr,
                                          nullptr, nullptr, 8192, 1024, 1024);
  // LN2: h1b (bf16 residual) + ff -> h2b
  ln_k<true><<<8192, 256, 0, stream>>>(h1b, ff, gamma, beta, h2b);
  hipMemsetAsync(cvec, 0, 8192 * sizeof(float), stream);
  gemm_k<true, 3><<<gg, 256, 0, stream>>>(h2b, wc1T, bc1, 1.f, nullptr,
                                          nullptr, wc2, cvec, 8192, 1024,
                                          1024);
  smm_part<true><<<dim3(8, 16), 256, 0, stream>>>(cvec, wl1, P1, 2048, 2048,
                                                  128, bc2);
  smm_red<true><<<8, 256, 0, stream>>>(P1, bl1, c3, 2048, 16);
  smm_part<false><<<dim3(1, 16), 256, 0, stream>>>(c3, wl2, P2, 2048, 256,
                                                   128, nullptr);
  smm_red<false><<<1, 256, 0, stream>>>(P2, bl2, (float*)d_out, 256, 16);
}

// Round 15
// 360.366 us; speedup vs baseline: 1.1413x; 1.0333x over previous
//
#include <hip/hip_runtime.h>

typedef unsigned short u16;
typedef unsigned int u32;
typedef __attribute__((ext_vector_type(4))) float f32x4;
typedef __attribute__((ext_vector_type(8))) short short8;
typedef __attribute__((ext_vector_type(4))) u32 u32x4;
typedef __attribute__((ext_vector_type(4))) u16 u16x4;

#define BB 4
#define LL 2048
#define DD 1024
#define HH 8
#define DHH 128

__device__ __forceinline__ u16 f2b(float f) {
  u32 u = __builtin_bit_cast(u32, f);
  u += 0x7fffu + ((u >> 16) & 1u);
  return (u16)(u >> 16);
}
__device__ __forceinline__ float b2f(u16 h) {
  u32 u = ((u32)h) << 16;
  return __builtin_bit_cast(float, u);
}
// raw v_exp_f32: D = 2^S0 (ISA §3) — exp2 with no mul
__device__ __forceinline__ float exp2_fast(float x) {
  float r;
  asm("v_exp_f32 %0, %1" : "=v"(r) : "v"(x));
  return r;
}
__device__ __forceinline__ u32 packbf(float a, float b) {
  return (u32)f2b(a) | ((u32)f2b(b) << 16);
}
__device__ __forceinline__ u32 bperm(int srcLane, u32 v) {
  return (u32)__builtin_amdgcn_ds_bpermute(srcLane << 2, (int)v);
}

#define GLDS16(g, l)                                                          \
  __builtin_amdgcn_global_load_lds(                                           \
      (const __attribute__((address_space(1))) void*)(g),                     \
      (__attribute__((address_space(3))) void*)(l), 16, 0, 0)

#define MFMA_BF16 __builtin_amdgcn_mfma_f32_16x16x32_bf16

// ---------------- elementwise fp32 -> bf16 ----------------
__global__ __launch_bounds__(256) void cvt_k(const float* __restrict__ X,
                                             u16* __restrict__ Xb, long n) {
  long i = ((long)blockIdx.x * 256 + threadIdx.x) * 4;
  if (i >= n) return;
  f32x4 v = *(const f32x4*)(X + i);
  u16x4 o;
#pragma unroll
  for (int k = 0; k < 4; k++) o[k] = f2b(v[k]);
  *(u16x4*)(Xb + i) = o;
}

// -------- 5x batched 1024x1024 fp32 -> bf16 transpose (z selects matrix) ---
__global__ __launch_bounds__(256) void tr5_k(
    const float* __restrict__ s0, const float* __restrict__ s1,
    const float* __restrict__ s2, const float* __restrict__ s3,
    const float* __restrict__ s4, u16* __restrict__ d0, u16* __restrict__ d1,
    u16* __restrict__ d2, u16* __restrict__ d3, u16* __restrict__ d4) {
  const float* W;
  u16* WT;
  switch (blockIdx.z) {
    case 0: W = s0; WT = d0; break;
    case 1: W = s1; WT = d1; break;
    case 2: W = s2; WT = d2; break;
    case 3: W = s3; WT = d3; break;
    default: W = s4; WT = d4; break;
  }
  __shared__ float tile[32][33];
  const int bx = blockIdx.x, by = blockIdx.y;
  const int tx = threadIdx.x & 31, ty = threadIdx.x >> 5;
#pragma unroll
  for (int i = 0; i < 4; i++)
    tile[ty + i * 8][tx] =
        W[(long)(by * 32 + ty + i * 8) * 1024 + bx * 32 + tx];
  __syncthreads();
#pragma unroll
  for (int i = 0; i < 4; i++)
    WT[(long)(bx * 32 + ty + i * 8) * 1024 + by * 32 + tx] =
        f2b(tile[tx][ty + i * 8]);
}

// ------- fused QKV GEMM: grid (24,64); sector = bxi>>3 in {Q,K,V} ---------
__global__ __launch_bounds__(256, 3) void qkv_k(
    const u16* __restrict__ A, const u16* __restrict__ QT,
    const u16* __restrict__ KT, const u16* __restrict__ VTw,
    const float* __restrict__ bq, const float* __restrict__ bk,
    const float* __restrict__ bv, float qscale, u16* __restrict__ Qo,
    u16* __restrict__ Ko, u16* __restrict__ Vo) {
  __shared__ u16 As[2][128 * 32];
  __shared__ u16 Bs[2][128 * 32];
  const int K = 1024;
  const int nwg = gridDim.x * gridDim.y;  // 1536, %8==0
  const int bid = blockIdx.x + blockIdx.y * gridDim.x;
  const int swz = (bid & 7) * (nwg >> 3) + (bid >> 3);
  const int bxi = swz % 24, byi = swz / 24;
  const int sector = bxi >> 3;  // 0=Q 1=K 2=V
  const u16* BT = sector == 0 ? QT : (sector == 1 ? KT : VTw);
  const float* bias = sector == 0 ? bq : (sector == 1 ? bk : bv);
  const float scale = sector == 0 ? qscale : 1.f;
  const int t = threadIdx.x;
  const int l = t & 63, w = t >> 6;
  const int lr = l & 15, lg = l >> 4;
  const int wr = (w >> 1) * 64, wc = (w & 1) * 64;
  const long bm = (long)byi * 128, bn = (long)(bxi & 7) * 128;
  const int srow = l >> 2;
  const int scol = (l & 3) * 8;
  const u16* Ag0 = A + (bm + w * 32 + srow) * (long)K + scol;
  const u16* Ag1 = A + (bm + w * 32 + 16 + srow) * (long)K + scol;
  const u16* Bg0 = BT + (bn + w * 32 + srow) * (long)K + scol;
  const u16* Bg1 = BT + (bn + w * 32 + 16 + srow) * (long)K + scol;
  const int wo = w * 1024;
  f32x4 acc[4][4] = {};
  GLDS16(Ag0, &As[0][wo]);
  GLDS16(Ag1, &As[0][wo + 512]);
  GLDS16(Bg0, &Bs[0][wo]);
  GLDS16(Bg1, &Bs[0][wo + 512]);
  __syncthreads();
  int cur = 0;
  for (int k0 = 0; k0 < K; k0 += 32) {
    const int nxt = cur ^ 1;
    if (k0 + 32 < K) {
      GLDS16(Ag0 + k0 + 32, &As[nxt][wo]);
      GLDS16(Ag1 + k0 + 32, &As[nxt][wo + 512]);
      GLDS16(Bg0 + k0 + 32, &Bs[nxt][wo]);
      GLDS16(Bg1 + k0 + 32, &Bs[nxt][wo + 512]);
    }
    short8 af[4], bf[4];
#pragma unroll
    for (int i = 0; i < 4; i++)
      af[i] = *(const short8*)&As[cur][(wr + i * 16 + lr) * 32 + lg * 8];
#pragma unroll
    for (int i = 0; i < 4; i++)
      bf[i] = *(const short8*)&Bs[cur][(wc + i * 16 + lr) * 32 + lg * 8];
#pragma unroll
    for (int i = 0; i < 4; i++)
#pragma unroll
      for (int j = 0; j < 4; j++)
        acc[i][j] = MFMA_BF16(af[i], bf[j], acc[i][j], 0, 0, 0);
    __syncthreads();
    cur = nxt;
  }
#pragma unroll
  for (int i = 0; i < 4; i++)
#pragma unroll
    for (int j = 0; j < 4; j++) {
      long col = bn + wc + j * 16 + lr;
      float bvv = bias[col];
      if (sector == 2) {  // V -> VT layout: VT[(b*1024+col)*2048 + l]
        long row0 = bm + wr + i * 16 + lg * 4;
        long b = row0 >> 11, l0 = row0 & 2047;
        u16x4 ov;
#pragma unroll
        for (int r = 0; r < 4; r++) ov[r] = f2b(acc[i][j][r] + bvv);
        *(u16x4*)(Vo + (b * 1024 + col) * 2048 + l0) = ov;
      } else {
        u16* Out = sector == 0 ? Qo : Ko;
#pragma unroll
        for (int r = 0; r < 4; r++) {
          long row = bm + wr + i * 16 + lg * 4 + r;
          Out[row * 1024 + col] = f2b((acc[i][j][r] + bvv) * scale);
        }
      }
    }
}

// ------- generic 128x128x32 GEMM, 2-phase dbuf ----------------------------
// OMODE: 1 = bf16 row-major (+relu opt); 3 = fused-c2 (no C store).
template <bool RELU, int OMODE>
__global__ __launch_bounds__(256, 3) void gemm_k(
    const u16* __restrict__ A, const u16* __restrict__ BT,
    const float* __restrict__ bias, u16* __restrict__ Cb,
    const float* __restrict__ w2, float* __restrict__ cvec, int M, int N,
    int K) {
  __shared__ u16 As[2][128 * 32];
  __shared__ u16 Bs[2][128 * 32];
  const int nwg = gridDim.x * gridDim.y;
  const int bid = blockIdx.x + blockIdx.y * gridDim.x;
  const int swz = (bid & 7) * (nwg >> 3) + (bid >> 3);
  const int bxi = swz % gridDim.x, byi = swz / gridDim.x;
  const int t = threadIdx.x;
  const int l = t & 63, w = t >> 6;
  const int lr = l & 15, lg = l >> 4;
  const int wr = (w >> 1) * 64, wc = (w & 1) * 64;
  const long bm = (long)byi * 128, bn = (long)bxi * 128;
  const int srow = l >> 2;
  const int scol = (l & 3) * 8;
  const u16* Ag0 = A + (bm + w * 32 + srow) * (long)K + scol;
  const u16* Ag1 = A + (bm + w * 32 + 16 + srow) * (long)K + scol;
  const u16* Bg0 = BT + (bn + w * 32 + srow) * (long)K + scol;
  const u16* Bg1 = BT + (bn + w * 32 + 16 + srow) * (long)K + scol;
  const int wo = w * 1024;
  f32x4 acc[4][4] = {};
  GLDS16(Ag0, &As[0][wo]);
  GLDS16(Ag1, &As[0][wo + 512]);
  GLDS16(Bg0, &Bs[0][wo]);
  GLDS16(Bg1, &Bs[0][wo + 512]);
  __syncthreads();
  int cur = 0;
  for (int k0 = 0; k0 < K; k0 += 32) {
    const int nxt = cur ^ 1;
    if (k0 + 32 < K) {
      GLDS16(Ag0 + k0 + 32, &As[nxt][wo]);
      GLDS16(Ag1 + k0 + 32, &As[nxt][wo + 512]);
      GLDS16(Bg0 + k0 + 32, &Bs[nxt][wo]);
      GLDS16(Bg1 + k0 + 32, &Bs[nxt][wo + 512]);
    }
    short8 af[4], bf[4];
#pragma unroll
    for (int i = 0; i < 4; i++)
      af[i] = *(const short8*)&As[cur][(wr + i * 16 + lr) * 32 + lg * 8];
#pragma unroll
    for (int i = 0; i < 4; i++)
      bf[i] = *(const short8*)&Bs[cur][(wc + i * 16 + lr) * 32 + lg * 8];
#pragma unroll
    for (int i = 0; i < 4; i++)
#pragma unroll
      for (int j = 0; j < 4; j++)
        acc[i][j] = MFMA_BF16(af[i], bf[j], acc[i][j], 0, 0, 0);
    __syncthreads();
    cur = nxt;
  }
  if (OMODE == 3) {
    float bvj[4], w2j[4];
#pragma unroll
    for (int j = 0; j < 4; j++) {
      long col = bn + wc + j * 16 + lr;
      bvj[j] = bias[col];
      w2j[j] = w2[col];
    }
#pragma unroll
    for (int i = 0; i < 4; i++)
#pragma unroll
      for (int r = 0; r < 4; r++) {
        float a2 = 0.f;
#pragma unroll
        for (int j = 0; j < 4; j++)
          a2 += fmaxf(acc[i][j][r] + bvj[j], 0.f) * w2j[j];
        a2 += __shfl_xor(a2, 1, 64);
        a2 += __shfl_xor(a2, 2, 64);
        a2 += __shfl_xor(a2, 4, 64);
        a2 += __shfl_xor(a2, 8, 64);
        if (lr == 0) {
          long row = bm + wr + i * 16 + lg * 4 + r;
          atomicAdd(&cvec[row], a2);
        }
      }
  } else {
#pragma unroll
    for (int i = 0; i < 4; i++)
#pragma unroll
      for (int j = 0; j < 4; j++) {
        long col = bn + wc + j * 16 + lr;
        float bv = bias[col];
#pragma unroll
        for (int r = 0; r < 4; r++) {
          long row = bm + wr + i * 16 + lg * 4 + r;
          float v2 = acc[i][j][r] + bv;
          if (RELU) v2 = fmaxf(v2, 0.f);
          Cb[row * N + col] = f2b(v2);
        }
      }
  }
}

// ---------------- flash attention v7b: bf16 ctx output ---------------------
__global__ __launch_bounds__(256, 2) void flash_k(const u16* __restrict__ Q,
                                                  const u16* __restrict__ Kb,
                                                  const u16* __restrict__ VT,
                                                  u16* __restrict__ ctx) {
  __shared__ u16 Ks2[2][64 * 128];
  __shared__ u16 Vs2[2][128 * 64];
  const int nwg = gridDim.x * gridDim.y;
  const int bid = blockIdx.x + blockIdx.y * gridDim.x;
  const int swz = (bid & 7) * (nwg >> 3) + (bid >> 3);
  const int bxi = swz % gridDim.x, byi = swz / gridDim.x;
  const int t = threadIdx.x;
  const int l = t & 63, w = t >> 6;  // w in 0..3
  const int lr = l & 15, lg = l >> 4;
  const int b = byi >> 3, h = byi & 7;
  const long kbase = ((long)b * LL) * DD + h * DHH;
  const long vtbase = ((long)(b * 8 + h) * DHH) * LL;
  const int q0 = bxi * 128;

  short8 qf0[4], qf1[4];
  {
    const u16* qp0 = Q + kbase + (long)(q0 + w * 32 + lr) * DD + lg * 8;
    const u16* qp1 = qp0 + 16 * DD;
#pragma unroll
    for (int c = 0; c < 4; c++) {
      qf0[c] = *(const short8*)(qp0 + c * 32);
      qf1[c] = *(const short8*)(qp1 + c * 32);
    }
  }
  f32x4 oacc0[8] = {}, oacc1[8] = {};
  float mprev0 = -1e30f, mprev1 = -1e30f;
  float lsum0 = 0.f, lsum1 = 0.f;

  const u16* kg[4];
  const u16* vg[4];
  u16* kl[4];
  u16* vl[4];
#pragma unroll
  for (int i = 0; i < 4; i++) {
    int rk = w * 16 + 4 * i + (l >> 4);
    kg[i] = Kb + kbase + (long)rk * DD + ((l & 15) ^ (rk & 7)) * 8;
    kl[i] = &Ks2[0][(w * 16 + 4 * i) * 128];
    int rv = w * 32 + 8 * i + (l >> 3);
    vg[i] = VT + vtbase + (long)rv * LL + ((l & 7) ^ (rv & 7)) * 8;
    vl[i] = &Vs2[0][(w * 32 + 8 * i) * 64];
  }
#pragma unroll
  for (int i = 0; i < 4; i++) {
    GLDS16(kg[i], kl[i]);
    GLDS16(vg[i], vl[i]);
  }
  __syncthreads();

  int colk[4], colv[2];
#pragma unroll
  for (int c = 0; c < 4; c++) colk[c] = (((c * 4 + lg) ^ (lr & 7)) * 8);
#pragma unroll
  for (int kk = 0; kk < 2; kk++) colv[kk] = (((kk * 4 + lg) ^ (lr & 7)) * 8);

  const int NT = LL / 64;
  for (int it = 0; it < NT; ++it) {
    const int cur = it & 1;
    if (it + 1 < NT) {
      const int ko = (cur ^ 1) * (64 * 128);
      const int vo = (cur ^ 1) * (128 * 64);
#pragma unroll
      for (int i = 0; i < 4; i++) {
        kg[i] += 64 * DD;
        vg[i] += 64;
        GLDS16(kg[i], kl[i] + ko);
        GLDS16(vg[i], vl[i] + vo);
      }
    }
    const u16* Kc = &Ks2[cur][0];
    const u16* Vc = &Vs2[cur][0];

    f32x4 s0[4] = {}, s1[4] = {};
#pragma unroll
    for (int jc = 0; jc < 4; jc++)
#pragma unroll
      for (int c = 0; c < 4; c++) {
        short8 kf = *(const short8*)&Kc[(jc * 16 + lr) * 128 + colk[c]];
        s0[jc] = MFMA_BF16(kf, qf0[c], s0[jc], 0, 0, 0);
        s1[jc] = MFMA_BF16(kf, qf1[c], s1[jc], 0, 0, 0);
      }

    float mx0 = fmaxf(fmaxf(s0[0][0], s0[0][1]), fmaxf(s0[0][2], s0[0][3]));
    float mx1 = fmaxf(fmaxf(s1[0][0], s1[0][1]), fmaxf(s1[0][2], s1[0][3]));
#pragma unroll
    for (int jc = 1; jc < 4; jc++) {
      mx0 = fmaxf(mx0, fmaxf(fmaxf(s0[jc][0], s0[jc][1]),
                             fmaxf(s0[jc][2], s0[jc][3])));
      mx1 = fmaxf(mx1, fmaxf(fmaxf(s1[jc][0], s1[jc][1]),
                             fmaxf(s1[jc][2], s1[jc][3])));
    }
    mx0 = fmaxf(mx0, __shfl_xor(mx0, 16, 64));
    mx0 = fmaxf(mx0, __shfl_xor(mx0, 32, 64));
    mx1 = fmaxf(mx1, __shfl_xor(mx1, 16, 64));
    mx1 = fmaxf(mx1, __shfl_xor(mx1, 32, 64));

    if (__any((int)((mx0 > mprev0 + 8.f) || (mx1 > mprev1 + 8.f)))) {
      float mn0 = fmaxf(mprev0, mx0), mn1 = fmaxf(mprev1, mx1);
      float al0 = exp2_fast(mprev0 - mn0), al1 = exp2_fast(mprev1 - mn1);
      mprev0 = mn0;
      mprev1 = mn1;
      lsum0 *= al0;
      lsum1 *= al1;
      float ar0[4], ar1[4];
#pragma unroll
      for (int r = 0; r < 4; r++) {
        ar0[r] = __shfl(al0, lg * 4 + r, 64);
        ar1[r] = __shfl(al1, lg * 4 + r, 64);
      }
#pragma unroll
      for (int d8 = 0; d8 < 8; d8++)
#pragma unroll
        for (int r = 0; r < 4; r++) {
          oacc0[d8][r] *= ar0[r];
          oacc1[d8][r] *= ar1[r];
        }
    }

    u32 pk0[4][2], pk1[4][2];
    float la0 = 0.f, la1 = 0.f;
#pragma unroll
    for (int jc = 0; jc < 4; jc++) {
      float a0 = exp2_fast(s0[jc][0] - mprev0);
      float a1 = exp2_fast(s0[jc][1] - mprev0);
      float a2 = exp2_fast(s0[jc][2] - mprev0);
      float a3 = exp2_fast(s0[jc][3] - mprev0);
      la0 += (a0 + a1) + (a2 + a3);
      pk0[jc][0] = packbf(a0, a1);
      pk0[jc][1] = packbf(a2, a3);
      float b0 = exp2_fast(s1[jc][0] - mprev1);
      float b1 = exp2_fast(s1[jc][1] - mprev1);
      float b2 = exp2_fast(s1[jc][2] - mprev1);
      float b3 = exp2_fast(s1[jc][3] - mprev1);
      la1 += (b0 + b1) + (b2 + b3);
      pk1[jc][0] = packbf(b0, b1);
      pk1[jc][1] = packbf(b2, b3);
    }
    lsum0 += la0;
    lsum1 += la1;

    short8 pf0[2], pf1[2];
#pragma unroll
    for (int kk = 0; kk < 2; kk++) {
      u32x4 av0, av1;
#pragma unroll
      for (int m = 0; m < 4; m++) {
        int srcl = lr + ((((lg & 1) << 1) + (m >> 1)) << 4);
        u32 x0 = bperm(srcl, pk0[2 * kk][m & 1]);
        u32 x1 = bperm(srcl, pk0[2 * kk + 1][m & 1]);
        av0[m] = (lg >> 1) ? x1 : x0;
        u32 y0 = bperm(srcl, pk1[2 * kk][m & 1]);
        u32 y1 = bperm(srcl, pk1[2 * kk + 1][m & 1]);
        av1[m] = (lg >> 1) ? y1 : y0;
      }
      pf0[kk] = __builtin_bit_cast(short8, av0);
      pf1[kk] = __builtin_bit_cast(short8, av1);
    }

#pragma unroll
    for (int kk = 0; kk < 2; kk++)
#pragma unroll
      for (int d8 = 0; d8 < 8; d8++) {
        short8 vf = *(const short8*)&Vc[(d8 * 16 + lr) * 64 + colv[kk]];
        oacc0[d8] = MFMA_BF16(pf0[kk], vf, oacc0[d8], 0, 0, 0);
        oacc1[d8] = MFMA_BF16(pf1[kk], vf, oacc1[d8], 0, 0, 0);
      }
    __syncthreads();
  }

  lsum0 += __shfl_xor(lsum0, 16, 64);
  lsum0 += __shfl_xor(lsum0, 32, 64);
  lsum1 += __shfl_xor(lsum1, 16, 64);
  lsum1 += __shfl_xor(lsum1, 32, 64);
#pragma unroll
  for (int r = 0; r < 4; r++) {
    float inv0 = 1.f / __shfl(lsum0, lg * 4 + r, 64);
    float inv1 = 1.f / __shfl(lsum1, lg * 4 + r, 64);
    u16* cp0 = ctx + kbase + (long)(q0 + w * 32 + lg * 4 + r) * DD;
    u16* cp1 = cp0 + 16 * DD;
#pragma unroll
    for (int d8 = 0; d8 < 8; d8++) {
      cp0[d8 * 16 + lr] = f2b(oacc0[d8][r] * inv0);
      cp1[d8 * 16 + lr] = f2b(oacc1[d8][r] * inv1);
    }
  }
}

// ---------------- residual + layernorm --------------------------------
// XB/RB: whether X / R inputs are bf16 (else fp32). Output bf16.
template <bool XB, bool RB>
__global__ __launch_bounds__(256) void ln_k(const void* __restrict__ Xp,
                                            const void* __restrict__ Rp,
                                            const float* __restrict__ gamma,
                                            const float* __restrict__ beta,
                                            u16* __restrict__ Hb) {
  const int row = blockIdx.x, t = threadIdx.x;
  const long off = (long)row * DD + t * 4;
  f32x4 v;
  if (XB) {
    u16x4 xv = *(const u16x4*)((const u16*)Xp + off);
#pragma unroll
    for (int i = 0; i < 4; i++) v[i] = b2f(xv[i]);
  } else {
    v = *(const f32x4*)((const float*)Xp + off);
  }
  if (RB) {
    u16x4 rv = *(const u16x4*)((const u16*)Rp + off);
#pragma unroll
    for (int i = 0; i < 4; i++) v[i] += b2f(rv[i]);
  } else {
    f32x4 rv = *(const f32x4*)((const float*)Rp + off);
#pragma unroll
    for (int i = 0; i < 4; i++) v[i] += rv[i];
  }
  float s = v[0] + v[1] + v[2] + v[3];
  float q = v[0] * v[0] + v[1] * v[1] + v[2] * v[2] + v[3] * v[3];
#pragma unroll
  for (int m = 32; m >= 1; m >>= 1) {
    s += __shfl_xor(s, m, 64);
    q += __shfl_xor(q, m, 64);
  }
  __shared__ float red[8];
  if ((t & 63) == 0) {
    red[t >> 6] = s;
    red[4 + (t >> 6)] = q;
  }
  __syncthreads();
  s = red[0] + red[1] + red[2] + red[3];
  q = red[4] + red[5] + red[6] + red[7];
  const float mean = s * (1.f / 1024.f);
  const float var = q * (1.f / 1024.f) - mean * mean;
  const float rstd = rsqrtf(var + 1e-12f);
  f32x4 g = *(const f32x4*)(gamma + t * 4);
  f32x4 be = *(const f32x4*)(beta + t * 4);
  u16x4 ob;
#pragma unroll
  for (int i = 0; i < 4; i++)
    ob[i] = f2b(g[i] * (v[i] - mean) * rstd + be[i]);
  *(u16x4*)(Hb + off) = ob;
}

// ---------------- small [4,Lr]@[Lr,N] GEMM: split-K partials + reduce -----
template <bool BR>
__global__ __launch_bounds__(256) void smm_part(const float* __restrict__ Cin,
                                                const float* __restrict__ W,
                                                float* __restrict__ P, int Lr,
                                                int N, int SL,
                                                const float* __restrict__ b0) {
  const int j = blockIdx.x * 256 + threadIdx.x;
  const int l0 = blockIdx.y * SL;
  const float bb = BR ? b0[0] : 0.f;
  float a0 = 0, a1 = 0, a2 = 0, a3 = 0;
  for (int ll = l0; ll < l0 + SL; ll++) {
    float wv = W[(long)ll * N + j];
    float c0 = Cin[ll], c1 = Cin[Lr + ll], c2 = Cin[2 * Lr + ll],
          c3 = Cin[3 * Lr + ll];
    if (BR) {
      c0 = fmaxf(c0 + bb, 0.f);
      c1 = fmaxf(c1 + bb, 0.f);
      c2 = fmaxf(c2 + bb, 0.f);
      c3 = fmaxf(c3 + bb, 0.f);
    }
    a0 += c0 * wv;
    a1 += c1 * wv;
    a2 += c2 * wv;
    a3 += c3 * wv;
  }
  float* Pp = P + ((long)blockIdx.y * 4) * N + j;
  Pp[0] = a0;
  Pp[N] = a1;
  Pp[2 * N] = a2;
  Pp[3 * N] = a3;
}

template <bool RELU>
__global__ __launch_bounds__(256) void smm_red(const float* __restrict__ P,
                                               const float* __restrict__ bias,
                                               float* __restrict__ Out, int N,
                                               int S) {
  const int j = blockIdx.x * 256 + threadIdx.x;
#pragma unroll
  for (int b = 0; b < 4; b++) {
    float a = 0;
    for (int s = 0; s < S; s++) a += P[((long)s * 4 + b) * N + j];
    a += bias[j];
    if (RELU) a = fmaxf(a, 0.f);
    Out[(long)b * N + j] = a;
  }
}

extern "C" void kernel_launch(void* const* d_in, const int* in_sizes, int n_in,
                              void* d_out, int out_size, void* d_ws,
                              size_t ws_size, hipStream_t stream) {
  (void)in_sizes; (void)n_in; (void)out_size; (void)ws_size;
  const float* x = (const float*)d_in[0];
  const float* wq = (const float*)d_in[1];
  const float* bq = (const float*)d_in[2];
  const float* wk = (const float*)d_in[3];
  const float* bk = (const float*)d_in[4];
  const float* wv = (const float*)d_in[5];
  const float* bv = (const float*)d_in[6];
  const float* gamma = (const float*)d_in[7];
  const float* beta = (const float*)d_in[8];
  const float* wff = (const float*)d_in[9];
  const float* bff = (const float*)d_in[10];
  const float* wc1 = (const float*)d_in[11];
  const float* bc1 = (const float*)d_in[12];
  const float* wc2 = (const float*)d_in[13];
  const float* bc2 = (const float*)d_in[14];
  const float* wl1 = (const float*)d_in[15];
  const float* bl1 = (const float*)d_in[16];
  const float* wl2 = (const float*)d_in[17];
  const float* bl2 = (const float*)d_in[18];

  char* wsp = (char*)d_ws;
  size_t off = 0;
  auto take = [&](size_t bytes) -> char* {
    char* p = wsp + off;
    off += (bytes + 255) & ~(size_t)255;
    return p;
  };
  u16* xb = (u16*)take((size_t)8192 * 1024 * 2);
  u16* wqT = (u16*)take((size_t)1024 * 1024 * 2);
  u16* wkT = (u16*)take((size_t)1024 * 1024 * 2);
  u16* wvT = (u16*)take((size_t)1024 * 1024 * 2);
  u16* wffT = (u16*)take((size_t)1024 * 1024 * 2);
  u16* wc1T = (u16*)take((size_t)1024 * 1024 * 2);
  u16* qb = (u16*)take((size_t)8192 * 1024 * 2);
  u16* kbuf = (u16*)take((size_t)8192 * 1024 * 2);
  u16* vT = (u16*)take((size_t)8192 * 1024 * 2);
  u16* ctxb = (u16*)take((size_t)8192 * 1024 * 2);  // bf16 now
  u16* h1b = (u16*)take((size_t)8192 * 1024 * 2);
  u16* ffb = (u16*)take((size_t)8192 * 1024 * 2);
  float* cvec = (float*)take(8192 * 4);
  float* c3 = (float*)take(8192 * 4);
  float* P1 = (float*)take((size_t)16 * 4 * 2048 * 4);
  float* P2 = (float*)take((size_t)16 * 4 * 256 * 4);
  u16* h2b = qb;  // dead after flash

  cvt_k<<<8192, 256, 0, stream>>>(x, xb, (long)8192 * 1024);
  tr5_k<<<dim3(32, 32, 5), 256, 0, stream>>>(wq, wk, wv, wff, wc1, wqT, wkT,
                                             wvT, wffT, wc1T);

  // fused QKV: grid (3*8, 64); Q scale folds 1/sqrt(128)*log2(e)
  qkv_k<<<dim3(24, 64), 256, 0, stream>>>(xb, wqT, wkT, wvT, bq, bk, bv,
                                          0.12751743f, qb, kbuf, vT);
  flash_k<<<dim3(16, 32), 256, 0, stream>>>(qb, kbuf, vT, ctxb);
  // LN1: x (fp32) + ctx (bf16) -> h1b (bf16)
  ln_k<false, true><<<8192, 256, 0, stream>>>(x, ctxb, gamma, beta, h1b);
  dim3 gg(8, 64);
  gemm_k<true, 1><<<gg, 256, 0, stream>>>(h1b, wffT, bff, ffb, nullptr,
                                          nullptr, 8192, 1024, 1024);
  // LN2: h1b (bf16) + ff (bf16) -> h2b
  ln_k<true, true><<<8192, 256, 0, stream>>>(h1b, ffb, gamma, beta, h2b);
  hipMemsetAsync(cvec, 0, 8192 * sizeof(float), stream);
  gemm_k<true, 3><<<gg, 256, 0, stream>>>(h2b, wc1T, bc1, nullptr, wc2, cvec,
                                          8192, 1024, 1024);
  smm_part<true><<<dim3(8, 16), 256, 0, stream>>>(cvec, wl1, P1, 2048, 2048,
                                                  128, bc2);
  smm_red<true><<<8, 256, 0, stream>>>(P1, bl1, c3, 2048, 16);
  smm_part<false><<<dim3(1, 16), 256, 0, stream>>>(c3, wl2, P2, 2048, 256,
                                                   128, nullptr);
  smm_red<false><<<1, 256, 0, stream>>>(P2, bl2, (float*)d_out, 256, 16);
}

// Round 16
// 358.879 us; speedup vs baseline: 1.1460x; 1.0041x over previous
//
#include <hip/hip_runtime.h>

typedef unsigned short u16;
typedef unsigned int u32;
typedef __attribute__((ext_vector_type(4))) float f32x4;
typedef __attribute__((ext_vector_type(8))) short short8;
typedef __attribute__((ext_vector_type(4))) u32 u32x4;
typedef __attribute__((ext_vector_type(4))) u16 u16x4;

#define BB 4
#define LL 2048
#define DD 1024
#define HH 8
#define DHH 128

__device__ __forceinline__ u16 f2b(float f) {
  u32 u = __builtin_bit_cast(u32, f);
  u += 0x7fffu + ((u >> 16) & 1u);
  return (u16)(u >> 16);
}
__device__ __forceinline__ float b2f(u16 h) {
  u32 u = ((u32)h) << 16;
  return __builtin_bit_cast(float, u);
}
// raw v_exp_f32: D = 2^S0 (ISA §3) — exp2 with no mul
__device__ __forceinline__ float exp2_fast(float x) {
  float r;
  asm("v_exp_f32 %0, %1" : "=v"(r) : "v"(x));
  return r;
}
__device__ __forceinline__ u32 packbf(float a, float b) {
  return (u32)f2b(a) | ((u32)f2b(b) << 16);
}
__device__ __forceinline__ u32 bperm(int srcLane, u32 v) {
  return (u32)__builtin_amdgcn_ds_bpermute(srcLane << 2, (int)v);
}

#define GLDS16(g, l)                                                          \
  __builtin_amdgcn_global_load_lds(                                           \
      (const __attribute__((address_space(1))) void*)(g),                     \
      (__attribute__((address_space(3))) void*)(l), 16, 0, 0)

#define MFMA_BF16 __builtin_amdgcn_mfma_f32_16x16x32_bf16

// ---------------- elementwise fp32 -> bf16 ----------------
__global__ __launch_bounds__(256) void cvt_k(const float* __restrict__ X,
                                             u16* __restrict__ Xb, long n) {
  long i = ((long)blockIdx.x * 256 + threadIdx.x) * 4;
  if (i >= n) return;
  f32x4 v = *(const f32x4*)(X + i);
  u16x4 o;
#pragma unroll
  for (int k = 0; k < 4; k++) o[k] = f2b(v[k]);
  *(u16x4*)(Xb + i) = o;
}

// -------- 5x batched 1024x1024 fp32 -> bf16 transpose (z selects matrix) ---
__global__ __launch_bounds__(256) void tr5_k(
    const float* __restrict__ s0, const float* __restrict__ s1,
    const float* __restrict__ s2, const float* __restrict__ s3,
    const float* __restrict__ s4, u16* __restrict__ d0, u16* __restrict__ d1,
    u16* __restrict__ d2, u16* __restrict__ d3, u16* __restrict__ d4) {
  const float* W;
  u16* WT;
  switch (blockIdx.z) {
    case 0: W = s0; WT = d0; break;
    case 1: W = s1; WT = d1; break;
    case 2: W = s2; WT = d2; break;
    case 3: W = s3; WT = d3; break;
    default: W = s4; WT = d4; break;
  }
  __shared__ float tile[32][33];
  const int bx = blockIdx.x, by = blockIdx.y;
  const int tx = threadIdx.x & 31, ty = threadIdx.x >> 5;
#pragma unroll
  for (int i = 0; i < 4; i++)
    tile[ty + i * 8][tx] =
        W[(long)(by * 32 + ty + i * 8) * 1024 + bx * 32 + tx];
  __syncthreads();
#pragma unroll
  for (int i = 0; i < 4; i++)
    WT[(long)(bx * 32 + ty + i * 8) * 1024 + by * 32 + tx] =
        f2b(tile[tx][ty + i * 8]);
}

// ------- fused QKV GEMM: grid (24,64); sector = bxi>>3 in {Q,K,V} ---------
__global__ __launch_bounds__(256, 3) void qkv_k(
    const u16* __restrict__ A, const u16* __restrict__ QT,
    const u16* __restrict__ KT, const u16* __restrict__ VTw,
    const float* __restrict__ bq, const float* __restrict__ bk,
    const float* __restrict__ bv, float qscale, u16* __restrict__ Qo,
    u16* __restrict__ Ko, u16* __restrict__ Vo) {
  __shared__ u16 As[2][128 * 32];
  __shared__ u16 Bs[2][128 * 32];
  const int K = 1024;
  const int nwg = gridDim.x * gridDim.y;  // 1536, %8==0
  const int bid = blockIdx.x + blockIdx.y * gridDim.x;
  const int swz = (bid & 7) * (nwg >> 3) + (bid >> 3);
  const int bxi = swz % 24, byi = swz / 24;
  const int sector = bxi >> 3;  // 0=Q 1=K 2=V
  const u16* BT = sector == 0 ? QT : (sector == 1 ? KT : VTw);
  const float* bias = sector == 0 ? bq : (sector == 1 ? bk : bv);
  const float scale = sector == 0 ? qscale : 1.f;
  const int t = threadIdx.x;
  const int l = t & 63, w = t >> 6;
  const int lr = l & 15, lg = l >> 4;
  const int wr = (w >> 1) * 64, wc = (w & 1) * 64;
  const long bm = (long)byi * 128, bn = (long)(bxi & 7) * 128;
  const int srow = l >> 2;
  const int scol = (l & 3) * 8;
  const u16* Ag0 = A + (bm + w * 32 + srow) * (long)K + scol;
  const u16* Ag1 = A + (bm + w * 32 + 16 + srow) * (long)K + scol;
  const u16* Bg0 = BT + (bn + w * 32 + srow) * (long)K + scol;
  const u16* Bg1 = BT + (bn + w * 32 + 16 + srow) * (long)K + scol;
  const int wo = w * 1024;
  f32x4 acc[4][4] = {};
  GLDS16(Ag0, &As[0][wo]);
  GLDS16(Ag1, &As[0][wo + 512]);
  GLDS16(Bg0, &Bs[0][wo]);
  GLDS16(Bg1, &Bs[0][wo + 512]);
  __syncthreads();
  int cur = 0;
  for (int k0 = 0; k0 < K; k0 += 32) {
    const int nxt = cur ^ 1;
    if (k0 + 32 < K) {
      GLDS16(Ag0 + k0 + 32, &As[nxt][wo]);
      GLDS16(Ag1 + k0 + 32, &As[nxt][wo + 512]);
      GLDS16(Bg0 + k0 + 32, &Bs[nxt][wo]);
      GLDS16(Bg1 + k0 + 32, &Bs[nxt][wo + 512]);
    }
    short8 af[4], bf[4];
#pragma unroll
    for (int i = 0; i < 4; i++)
      af[i] = *(const short8*)&As[cur][(wr + i * 16 + lr) * 32 + lg * 8];
#pragma unroll
    for (int i = 0; i < 4; i++)
      bf[i] = *(const short8*)&Bs[cur][(wc + i * 16 + lr) * 32 + lg * 8];
#pragma unroll
    for (int i = 0; i < 4; i++)
#pragma unroll
      for (int j = 0; j < 4; j++)
        acc[i][j] = MFMA_BF16(af[i], bf[j], acc[i][j], 0, 0, 0);
    __syncthreads();
    cur = nxt;
  }
#pragma unroll
  for (int i = 0; i < 4; i++)
#pragma unroll
    for (int j = 0; j < 4; j++) {
      long col = bn + wc + j * 16 + lr;
      float bvv = bias[col];
      if (sector == 2) {  // V -> VT layout: VT[(b*1024+col)*2048 + l]
        long row0 = bm + wr + i * 16 + lg * 4;
        long b = row0 >> 11, l0 = row0 & 2047;
        u16x4 ov;
#pragma unroll
        for (int r = 0; r < 4; r++) ov[r] = f2b(acc[i][j][r] + bvv);
        *(u16x4*)(Vo + (b * 1024 + col) * 2048 + l0) = ov;
      } else {
        u16* Out = sector == 0 ? Qo : Ko;
#pragma unroll
        for (int r = 0; r < 4; r++) {
          long row = bm + wr + i * 16 + lg * 4 + r;
          Out[row * 1024 + col] = f2b((acc[i][j][r] + bvv) * scale);
        }
      }
    }
}

// ------- generic 128x128x32 GEMM, 2-phase dbuf ----------------------------
// OMODE: 1 = bf16 row-major (+relu opt); 3 = fused-c2 (no C store).
template <bool RELU, int OMODE>
__global__ __launch_bounds__(256, 3) void gemm_k(
    const u16* __restrict__ A, const u16* __restrict__ BT,
    const float* __restrict__ bias, u16* __restrict__ Cb,
    const float* __restrict__ w2, float* __restrict__ cvec, int M, int N,
    int K) {
  __shared__ u16 As[2][128 * 32];
  __shared__ u16 Bs[2][128 * 32];
  const int nwg = gridDim.x * gridDim.y;
  const int bid = blockIdx.x + blockIdx.y * gridDim.x;
  const int swz = (bid & 7) * (nwg >> 3) + (bid >> 3);
  const int bxi = swz % gridDim.x, byi = swz / gridDim.x;
  const int t = threadIdx.x;
  const int l = t & 63, w = t >> 6;
  const int lr = l & 15, lg = l >> 4;
  const int wr = (w >> 1) * 64, wc = (w & 1) * 64;
  const long bm = (long)byi * 128, bn = (long)bxi * 128;
  const int srow = l >> 2;
  const int scol = (l & 3) * 8;
  const u16* Ag0 = A + (bm + w * 32 + srow) * (long)K + scol;
  const u16* Ag1 = A + (bm + w * 32 + 16 + srow) * (long)K + scol;
  const u16* Bg0 = BT + (bn + w * 32 + srow) * (long)K + scol;
  const u16* Bg1 = BT + (bn + w * 32 + 16 + srow) * (long)K + scol;
  const int wo = w * 1024;
  f32x4 acc[4][4] = {};
  GLDS16(Ag0, &As[0][wo]);
  GLDS16(Ag1, &As[0][wo + 512]);
  GLDS16(Bg0, &Bs[0][wo]);
  GLDS16(Bg1, &Bs[0][wo + 512]);
  __syncthreads();
  int cur = 0;
  for (int k0 = 0; k0 < K; k0 += 32) {
    const int nxt = cur ^ 1;
    if (k0 + 32 < K) {
      GLDS16(Ag0 + k0 + 32, &As[nxt][wo]);
      GLDS16(Ag1 + k0 + 32, &As[nxt][wo + 512]);
      GLDS16(Bg0 + k0 + 32, &Bs[nxt][wo]);
      GLDS16(Bg1 + k0 + 32, &Bs[nxt][wo + 512]);
    }
    short8 af[4], bf[4];
#pragma unroll
    for (int i = 0; i < 4; i++)
      af[i] = *(const short8*)&As[cur][(wr + i * 16 + lr) * 32 + lg * 8];
#pragma unroll
    for (int i = 0; i < 4; i++)
      bf[i] = *(const short8*)&Bs[cur][(wc + i * 16 + lr) * 32 + lg * 8];
#pragma unroll
    for (int i = 0; i < 4; i++)
#pragma unroll
      for (int j = 0; j < 4; j++)
        acc[i][j] = MFMA_BF16(af[i], bf[j], acc[i][j], 0, 0, 0);
    __syncthreads();
    cur = nxt;
  }
  if (OMODE == 3) {
    float bvj[4], w2j[4];
#pragma unroll
    for (int j = 0; j < 4; j++) {
      long col = bn + wc + j * 16 + lr;
      bvj[j] = bias[col];
      w2j[j] = w2[col];
    }
#pragma unroll
    for (int i = 0; i < 4; i++)
#pragma unroll
      for (int r = 0; r < 4; r++) {
        float a2 = 0.f;
#pragma unroll
        for (int j = 0; j < 4; j++)
          a2 += fmaxf(acc[i][j][r] + bvj[j], 0.f) * w2j[j];
        a2 += __shfl_xor(a2, 1, 64);
        a2 += __shfl_xor(a2, 2, 64);
        a2 += __shfl_xor(a2, 4, 64);
        a2 += __shfl_xor(a2, 8, 64);
        if (lr == 0) {
          long row = bm + wr + i * 16 + lg * 4 + r;
          atomicAdd(&cvec[row], a2);
        }
      }
  } else {
#pragma unroll
    for (int i = 0; i < 4; i++)
#pragma unroll
      for (int j = 0; j < 4; j++) {
        long col = bn + wc + j * 16 + lr;
        float bv = bias[col];
#pragma unroll
        for (int r = 0; r < 4; r++) {
          long row = bm + wr + i * 16 + lg * 4 + r;
          float v2 = acc[i][j][r] + bv;
          if (RELU) v2 = fmaxf(v2, 0.f);
          Cb[row * N + col] = f2b(v2);
        }
      }
  }
}

// ---------------- flash attention v7c: + T5 setprio around MFMA clusters ---
__global__ __launch_bounds__(256, 2) void flash_k(const u16* __restrict__ Q,
                                                  const u16* __restrict__ Kb,
                                                  const u16* __restrict__ VT,
                                                  u16* __restrict__ ctx) {
  __shared__ u16 Ks2[2][64 * 128];
  __shared__ u16 Vs2[2][128 * 64];
  const int nwg = gridDim.x * gridDim.y;
  const int bid = blockIdx.x + blockIdx.y * gridDim.x;
  const int swz = (bid & 7) * (nwg >> 3) + (bid >> 3);
  const int bxi = swz % gridDim.x, byi = swz / gridDim.x;
  const int t = threadIdx.x;
  const int l = t & 63, w = t >> 6;  // w in 0..3
  const int lr = l & 15, lg = l >> 4;
  const int b = byi >> 3, h = byi & 7;
  const long kbase = ((long)b * LL) * DD + h * DHH;
  const long vtbase = ((long)(b * 8 + h) * DHH) * LL;
  const int q0 = bxi * 128;

  short8 qf0[4], qf1[4];
  {
    const u16* qp0 = Q + kbase + (long)(q0 + w * 32 + lr) * DD + lg * 8;
    const u16* qp1 = qp0 + 16 * DD;
#pragma unroll
    for (int c = 0; c < 4; c++) {
      qf0[c] = *(const short8*)(qp0 + c * 32);
      qf1[c] = *(const short8*)(qp1 + c * 32);
    }
  }
  f32x4 oacc0[8] = {}, oacc1[8] = {};
  float mprev0 = -1e30f, mprev1 = -1e30f;
  float lsum0 = 0.f, lsum1 = 0.f;

  const u16* kg[4];
  const u16* vg[4];
  u16* kl[4];
  u16* vl[4];
#pragma unroll
  for (int i = 0; i < 4; i++) {
    int rk = w * 16 + 4 * i + (l >> 4);
    kg[i] = Kb + kbase + (long)rk * DD + ((l & 15) ^ (rk & 7)) * 8;
    kl[i] = &Ks2[0][(w * 16 + 4 * i) * 128];
    int rv = w * 32 + 8 * i + (l >> 3);
    vg[i] = VT + vtbase + (long)rv * LL + ((l & 7) ^ (rv & 7)) * 8;
    vl[i] = &Vs2[0][(w * 32 + 8 * i) * 64];
  }
#pragma unroll
  for (int i = 0; i < 4; i++) {
    GLDS16(kg[i], kl[i]);
    GLDS16(vg[i], vl[i]);
  }
  __syncthreads();

  int colk[4], colv[2];
#pragma unroll
  for (int c = 0; c < 4; c++) colk[c] = (((c * 4 + lg) ^ (lr & 7)) * 8);
#pragma unroll
  for (int kk = 0; kk < 2; kk++) colv[kk] = (((kk * 4 + lg) ^ (lr & 7)) * 8);

  const int NT = LL / 64;
  for (int it = 0; it < NT; ++it) {
    const int cur = it & 1;
    if (it + 1 < NT) {
      const int ko = (cur ^ 1) * (64 * 128);
      const int vo = (cur ^ 1) * (128 * 64);
#pragma unroll
      for (int i = 0; i < 4; i++) {
        kg[i] += 64 * DD;
        vg[i] += 64;
        GLDS16(kg[i], kl[i] + ko);
        GLDS16(vg[i], vl[i] + vo);
      }
    }
    const u16* Kc = &Ks2[cur][0];
    const u16* Vc = &Vs2[cur][0];

    f32x4 s0[4] = {}, s1[4] = {};
    __builtin_amdgcn_s_setprio(1);
#pragma unroll
    for (int jc = 0; jc < 4; jc++)
#pragma unroll
      for (int c = 0; c < 4; c++) {
        short8 kf = *(const short8*)&Kc[(jc * 16 + lr) * 128 + colk[c]];
        s0[jc] = MFMA_BF16(kf, qf0[c], s0[jc], 0, 0, 0);
        s1[jc] = MFMA_BF16(kf, qf1[c], s1[jc], 0, 0, 0);
      }
    __builtin_amdgcn_s_setprio(0);

    float mx0 = fmaxf(fmaxf(s0[0][0], s0[0][1]), fmaxf(s0[0][2], s0[0][3]));
    float mx1 = fmaxf(fmaxf(s1[0][0], s1[0][1]), fmaxf(s1[0][2], s1[0][3]));
#pragma unroll
    for (int jc = 1; jc < 4; jc++) {
      mx0 = fmaxf(mx0, fmaxf(fmaxf(s0[jc][0], s0[jc][1]),
                             fmaxf(s0[jc][2], s0[jc][3])));
      mx1 = fmaxf(mx1, fmaxf(fmaxf(s1[jc][0], s1[jc][1]),
                             fmaxf(s1[jc][2], s1[jc][3])));
    }
    mx0 = fmaxf(mx0, __shfl_xor(mx0, 16, 64));
    mx0 = fmaxf(mx0, __shfl_xor(mx0, 32, 64));
    mx1 = fmaxf(mx1, __shfl_xor(mx1, 16, 64));
    mx1 = fmaxf(mx1, __shfl_xor(mx1, 32, 64));

    if (__any((int)((mx0 > mprev0 + 8.f) || (mx1 > mprev1 + 8.f)))) {
      float mn0 = fmaxf(mprev0, mx0), mn1 = fmaxf(mprev1, mx1);
      float al0 = exp2_fast(mprev0 - mn0), al1 = exp2_fast(mprev1 - mn1);
      mprev0 = mn0;
      mprev1 = mn1;
      lsum0 *= al0;
      lsum1 *= al1;
      float ar0[4], ar1[4];
#pragma unroll
      for (int r = 0; r < 4; r++) {
        ar0[r] = __shfl(al0, lg * 4 + r, 64);
        ar1[r] = __shfl(al1, lg * 4 + r, 64);
      }
#pragma unroll
      for (int d8 = 0; d8 < 8; d8++)
#pragma unroll
        for (int r = 0; r < 4; r++) {
          oacc0[d8][r] *= ar0[r];
          oacc1[d8][r] *= ar1[r];
        }
    }

    u32 pk0[4][2], pk1[4][2];
    float la0 = 0.f, la1 = 0.f;
#pragma unroll
    for (int jc = 0; jc < 4; jc++) {
      float a0 = exp2_fast(s0[jc][0] - mprev0);
      float a1 = exp2_fast(s0[jc][1] - mprev0);
      float a2 = exp2_fast(s0[jc][2] - mprev0);
      float a3 = exp2_fast(s0[jc][3] - mprev0);
      la0 += (a0 + a1) + (a2 + a3);
      pk0[jc][0] = packbf(a0, a1);
      pk0[jc][1] = packbf(a2, a3);
      float b0 = exp2_fast(s1[jc][0] - mprev1);
      float b1 = exp2_fast(s1[jc][1] - mprev1);
      float b2 = exp2_fast(s1[jc][2] - mprev1);
      float b3 = exp2_fast(s1[jc][3] - mprev1);
      la1 += (b0 + b1) + (b2 + b3);
      pk1[jc][0] = packbf(b0, b1);
      pk1[jc][1] = packbf(b2, b3);
    }
    lsum0 += la0;
    lsum1 += la1;

    short8 pf0[2], pf1[2];
#pragma unroll
    for (int kk = 0; kk < 2; kk++) {
      u32x4 av0, av1;
#pragma unroll
      for (int m = 0; m < 4; m++) {
        int srcl = lr + ((((lg & 1) << 1) + (m >> 1)) << 4);
        u32 x0 = bperm(srcl, pk0[2 * kk][m & 1]);
        u32 x1 = bperm(srcl, pk0[2 * kk + 1][m & 1]);
        av0[m] = (lg >> 1) ? x1 : x0;
        u32 y0 = bperm(srcl, pk1[2 * kk][m & 1]);
        u32 y1 = bperm(srcl, pk1[2 * kk + 1][m & 1]);
        av1[m] = (lg >> 1) ? y1 : y0;
      }
      pf0[kk] = __builtin_bit_cast(short8, av0);
      pf1[kk] = __builtin_bit_cast(short8, av1);
    }

    __builtin_amdgcn_s_setprio(1);
#pragma unroll
    for (int kk = 0; kk < 2; kk++)
#pragma unroll
      for (int d8 = 0; d8 < 8; d8++) {
        short8 vf = *(const short8*)&Vc[(d8 * 16 + lr) * 64 + colv[kk]];
        oacc0[d8] = MFMA_BF16(pf0[kk], vf, oacc0[d8], 0, 0, 0);
        oacc1[d8] = MFMA_BF16(pf1[kk], vf, oacc1[d8], 0, 0, 0);
      }
    __builtin_amdgcn_s_setprio(0);
    __syncthreads();
  }

  lsum0 += __shfl_xor(lsum0, 16, 64);
  lsum0 += __shfl_xor(lsum0, 32, 64);
  lsum1 += __shfl_xor(lsum1, 16, 64);
  lsum1 += __shfl_xor(lsum1, 32, 64);
#pragma unroll
  for (int r = 0; r < 4; r++) {
    float inv0 = 1.f / __shfl(lsum0, lg * 4 + r, 64);
    float inv1 = 1.f / __shfl(lsum1, lg * 4 + r, 64);
    u16* cp0 = ctx + kbase + (long)(q0 + w * 32 + lg * 4 + r) * DD;
    u16* cp1 = cp0 + 16 * DD;
#pragma unroll
    for (int d8 = 0; d8 < 8; d8++) {
      cp0[d8 * 16 + lr] = f2b(oacc0[d8][r] * inv0);
      cp1[d8 * 16 + lr] = f2b(oacc1[d8][r] * inv1);
    }
  }
}

// ---------------- residual + layernorm --------------------------------
// XB/RB: whether X / R inputs are bf16 (else fp32). Output bf16.
template <bool XB, bool RB>
__global__ __launch_bounds__(256) void ln_k(const void* __restrict__ Xp,
                                            const void* __restrict__ Rp,
                                            const float* __restrict__ gamma,
                                            const float* __restrict__ beta,
                                            u16* __restrict__ Hb) {
  const int row = blockIdx.x, t = threadIdx.x;
  const long off = (long)row * DD + t * 4;
  f32x4 v;
  if (XB) {
    u16x4 xv = *(const u16x4*)((const u16*)Xp + off);
#pragma unroll
    for (int i = 0; i < 4; i++) v[i] = b2f(xv[i]);
  } else {
    v = *(const f32x4*)((const float*)Xp + off);
  }
  if (RB) {
    u16x4 rv = *(const u16x4*)((const u16*)Rp + off);
#pragma unroll
    for (int i = 0; i < 4; i++) v[i] += b2f(rv[i]);
  } else {
    f32x4 rv = *(const f32x4*)((const float*)Rp + off);
#pragma unroll
    for (int i = 0; i < 4; i++) v[i] += rv[i];
  }
  float s = v[0] + v[1] + v[2] + v[3];
  float q = v[0] * v[0] + v[1] * v[1] + v[2] * v[2] + v[3] * v[3];
#pragma unroll
  for (int m = 32; m >= 1; m >>= 1) {
    s += __shfl_xor(s, m, 64);
    q += __shfl_xor(q, m, 64);
  }
  __shared__ float red[8];
  if ((t & 63) == 0) {
    red[t >> 6] = s;
    red[4 + (t >> 6)] = q;
  }
  __syncthreads();
  s = red[0] + red[1] + red[2] + red[3];
  q = red[4] + red[5] + red[6] + red[7];
  const float mean = s * (1.f / 1024.f);
  const float var = q * (1.f / 1024.f) - mean * mean;
  const float rstd = rsqrtf(var + 1e-12f);
  f32x4 g = *(const f32x4*)(gamma + t * 4);
  f32x4 be = *(const f32x4*)(beta + t * 4);
  u16x4 ob;
#pragma unroll
  for (int i = 0; i < 4; i++)
    ob[i] = f2b(g[i] * (v[i] - mean) * rstd + be[i]);
  *(u16x4*)(Hb + off) = ob;
}

// ---------------- small [4,Lr]@[Lr,N] GEMM: split-K partials + reduce -----
template <bool BR>
__global__ __launch_bounds__(256) void smm_part(const float* __restrict__ Cin,
                                                const float* __restrict__ W,
                                                float* __restrict__ P, int Lr,
                                                int N, int SL,
                                                const float* __restrict__ b0) {
  const int j = blockIdx.x * 256 + threadIdx.x;
  const int l0 = blockIdx.y * SL;
  const float bb = BR ? b0[0] : 0.f;
  float a0 = 0, a1 = 0, a2 = 0, a3 = 0;
  for (int ll = l0; ll < l0 + SL; ll++) {
    float wv = W[(long)ll * N + j];
    float c0 = Cin[ll], c1 = Cin[Lr + ll], c2 = Cin[2 * Lr + ll],
          c3 = Cin[3 * Lr + ll];
    if (BR) {
      c0 = fmaxf(c0 + bb, 0.f);
      c1 = fmaxf(c1 + bb, 0.f);
      c2 = fmaxf(c2 + bb, 0.f);
      c3 = fmaxf(c3 + bb, 0.f);
    }
    a0 += c0 * wv;
    a1 += c1 * wv;
    a2 += c2 * wv;
    a3 += c3 * wv;
  }
  float* Pp = P + ((long)blockIdx.y * 4) * N + j;
  Pp[0] = a0;
  Pp[N] = a1;
  Pp[2 * N] = a2;
  Pp[3 * N] = a3;
}

template <bool RELU>
__global__ __launch_bounds__(256) void smm_red(const float* __restrict__ P,
                                               const float* __restrict__ bias,
                                               float* __restrict__ Out, int N,
                                               int S) {
  const int j = blockIdx.x * 256 + threadIdx.x;
#pragma unroll
  for (int b = 0; b < 4; b++) {
    float a = 0;
    for (int s = 0; s < S; s++) a += P[((long)s * 4 + b) * N + j];
    a += bias[j];
    if (RELU) a = fmaxf(a, 0.f);
    Out[(long)b * N + j] = a;
  }
}

extern "C" void kernel_launch(void* const* d_in, const int* in_sizes, int n_in,
                              void* d_out, int out_size, void* d_ws,
                              size_t ws_size, hipStream_t stream) {
  (void)in_sizes; (void)n_in; (void)out_size; (void)ws_size;
  const float* x = (const float*)d_in[0];
  const float* wq = (const float*)d_in[1];
  const float* bq = (const float*)d_in[2];
  const float* wk = (const float*)d_in[3];
  const float* bk = (const float*)d_in[4];
  const float* wv = (const float*)d_in[5];
  const float* bv = (const float*)d_in[6];
  const float* gamma = (const float*)d_in[7];
  const float* beta = (const float*)d_in[8];
  const float* wff = (const float*)d_in[9];
  const float* bff = (const float*)d_in[10];
  const float* wc1 = (const float*)d_in[11];
  const float* bc1 = (const float*)d_in[12];
  const float* wc2 = (const float*)d_in[13];
  const float* bc2 = (const float*)d_in[14];
  const float* wl1 = (const float*)d_in[15];
  const float* bl1 = (const float*)d_in[16];
  const float* wl2 = (const float*)d_in[17];
  const float* bl2 = (const float*)d_in[18];

  char* wsp = (char*)d_ws;
  size_t off = 0;
  auto take = [&](size_t bytes) -> char* {
    char* p = wsp + off;
    off += (bytes + 255) & ~(size_t)255;
    return p;
  };
  u16* xb = (u16*)take((size_t)8192 * 1024 * 2);
  u16* wqT = (u16*)take((size_t)1024 * 1024 * 2);
  u16* wkT = (u16*)take((size_t)1024 * 1024 * 2);
  u16* wvT = (u16*)take((size_t)1024 * 1024 * 2);
  u16* wffT = (u16*)take((size_t)1024 * 1024 * 2);
  u16* wc1T = (u16*)take((size_t)1024 * 1024 * 2);
  u16* qb = (u16*)take((size_t)8192 * 1024 * 2);
  u16* kbuf = (u16*)take((size_t)8192 * 1024 * 2);
  u16* vT = (u16*)take((size_t)8192 * 1024 * 2);
  u16* ctxb = (u16*)take((size_t)8192 * 1024 * 2);
  u16* h1b = (u16*)take((size_t)8192 * 1024 * 2);
  u16* ffb = (u16*)take((size_t)8192 * 1024 * 2);
  float* cvec = (float*)take(8192 * 4);
  float* c3 = (float*)take(8192 * 4);
  float* P1 = (float*)take((size_t)16 * 4 * 2048 * 4);
  float* P2 = (float*)take((size_t)16 * 4 * 256 * 4);
  u16* h2b = qb;  // dead after flash

  cvt_k<<<8192, 256, 0, stream>>>(x, xb, (long)8192 * 1024);
  tr5_k<<<dim3(32, 32, 5), 256, 0, stream>>>(wq, wk, wv, wff, wc1, wqT, wkT,
                                             wvT, wffT, wc1T);

  // fused QKV: grid (3*8, 64); Q scale folds 1/sqrt(128)*log2(e)
  qkv_k<<<dim3(24, 64), 256, 0, stream>>>(xb, wqT, wkT, wvT, bq, bk, bv,
                                          0.12751743f, qb, kbuf, vT);
  flash_k<<<dim3(16, 32), 256, 0, stream>>>(qb, kbuf, vT, ctxb);
  // LN1: xb (bf16) + ctx (bf16) -> h1b (bf16)
  ln_k<true, true><<<8192, 256, 0, stream>>>(xb, ctxb, gamma, beta, h1b);
  dim3 gg(8, 64);
  gemm_k<true, 1><<<gg, 256, 0, stream>>>(h1b, wffT, bff, ffb, nullptr,
                                          nullptr, 8192, 1024, 1024);
  // LN2: h1b (bf16) + ff (bf16) -> h2b
  ln_k<true, true><<<8192, 256, 0, stream>>>(h1b, ffb, gamma, beta, h2b);
  hipMemsetAsync(cvec, 0, 8192 * sizeof(float), stream);
  gemm_k<true, 3><<<gg, 256, 0, stream>>>(h2b, wc1T, bc1, nullptr, wc2, cvec,
                                          8192, 1024, 1024);
  smm_part<true><<<dim3(8, 16), 256, 0, stream>>>(cvec, wl1, P1, 2048, 2048,
                                                  128, bc2);
  smm_red<true><<<8, 256, 0, stream>>>(P1, bl1, c3, 2048, 16);
  smm_part<false><<<dim3(1, 16), 256, 0, stream>>>(c3, wl2, P2, 2048, 256,
                                                   128, nullptr);
  smm_red<false><<<1, 256, 0, stream>>>(P2, bl2, (float*)d_out, 256, 16);
}

// Round 17
// 355.730 us; speedup vs baseline: 1.1561x; 1.0089x over previous
//
#include <hip/hip_runtime.h>

typedef unsigned short u16;
typedef unsigned int u32;
typedef __attribute__((ext_vector_type(4))) float f32x4;
typedef __attribute__((ext_vector_type(8))) short short8;
typedef __attribute__((ext_vector_type(4))) u32 u32x4;
typedef __attribute__((ext_vector_type(4))) u16 u16x4;

#define BB 4
#define LL 2048
#define DD 1024
#define HH 8
#define DHH 128

__device__ __forceinline__ u16 f2b(float f) {
  u32 u = __builtin_bit_cast(u32, f);
  u += 0x7fffu + ((u >> 16) & 1u);
  return (u16)(u >> 16);
}
__device__ __forceinline__ float b2f(u16 h) {
  u32 u = ((u32)h) << 16;
  return __builtin_bit_cast(float, u);
}
// raw v_exp_f32: D = 2^S0 (ISA §3) — exp2 with no mul
__device__ __forceinline__ float exp2_fast(float x) {
  float r;
  asm("v_exp_f32 %0, %1" : "=v"(r) : "v"(x));
  return r;
}
__device__ __forceinline__ u32 packbf(float a, float b) {
  return (u32)f2b(a) | ((u32)f2b(b) << 16);
}
__device__ __forceinline__ u32 bperm(int srcLane, u32 v) {
  return (u32)__builtin_amdgcn_ds_bpermute(srcLane << 2, (int)v);
}

#define GLDS16(g, l)                                                          \
  __builtin_amdgcn_global_load_lds(                                           \
      (const __attribute__((address_space(1))) void*)(g),                     \
      (__attribute__((address_space(3))) void*)(l), 16, 0, 0)

#define MFMA_BF16 __builtin_amdgcn_mfma_f32_16x16x32_bf16

// ---------------- elementwise fp32 -> bf16 ----------------
__global__ __launch_bounds__(256) void cvt_k(const float* __restrict__ X,
                                             u16* __restrict__ Xb, long n) {
  long i = ((long)blockIdx.x * 256 + threadIdx.x) * 4;
  if (i >= n) return;
  f32x4 v = *(const f32x4*)(X + i);
  u16x4 o;
#pragma unroll
  for (int k = 0; k < 4; k++) o[k] = f2b(v[k]);
  *(u16x4*)(Xb + i) = o;
}

// -------- 5x batched 1024x1024 fp32 -> bf16 transpose (z selects matrix) ---
__global__ __launch_bounds__(256) void tr5_k(
    const float* __restrict__ s0, const float* __restrict__ s1,
    const float* __restrict__ s2, const float* __restrict__ s3,
    const float* __restrict__ s4, u16* __restrict__ d0, u16* __restrict__ d1,
    u16* __restrict__ d2, u16* __restrict__ d3, u16* __restrict__ d4) {
  const float* W;
  u16* WT;
  switch (blockIdx.z) {
    case 0: W = s0; WT = d0; break;
    case 1: W = s1; WT = d1; break;
    case 2: W = s2; WT = d2; break;
    case 3: W = s3; WT = d3; break;
    default: W = s4; WT = d4; break;
  }
  __shared__ float tile[32][33];
  const int bx = blockIdx.x, by = blockIdx.y;
  const int tx = threadIdx.x & 31, ty = threadIdx.x >> 5;
#pragma unroll
  for (int i = 0; i < 4; i++)
    tile[ty + i * 8][tx] =
        W[(long)(by * 32 + ty + i * 8) * 1024 + bx * 32 + tx];
  __syncthreads();
#pragma unroll
  for (int i = 0; i < 4; i++)
    WT[(long)(bx * 32 + ty + i * 8) * 1024 + by * 32 + tx] =
        f2b(tile[tx][ty + i * 8]);
}

// ------- fused QKV GEMM: grid (24,64); sector = bxi>>3 in {Q,K,V} ---------
__global__ __launch_bounds__(256, 3) void qkv_k(
    const u16* __restrict__ A, const u16* __restrict__ QT,
    const u16* __restrict__ KT, const u16* __restrict__ VTw,
    const float* __restrict__ bq, const float* __restrict__ bk,
    const float* __restrict__ bv, float qscale, u16* __restrict__ Qo,
    u16* __restrict__ Ko, u16* __restrict__ Vo) {
  __shared__ u16 As[2][128 * 32];
  __shared__ u16 Bs[2][128 * 32];
  const int K = 1024;
  const int nwg = gridDim.x * gridDim.y;  // 1536, %8==0
  const int bid = blockIdx.x + blockIdx.y * gridDim.x;
  const int swz = (bid & 7) * (nwg >> 3) + (bid >> 3);
  const int bxi = swz % 24, byi = swz / 24;
  const int sector = bxi >> 3;  // 0=Q 1=K 2=V
  const u16* BT = sector == 0 ? QT : (sector == 1 ? KT : VTw);
  const float* bias = sector == 0 ? bq : (sector == 1 ? bk : bv);
  const float scale = sector == 0 ? qscale : 1.f;
  const int t = threadIdx.x;
  const int l = t & 63, w = t >> 6;
  const int lr = l & 15, lg = l >> 4;
  const int wr = (w >> 1) * 64, wc = (w & 1) * 64;
  const long bm = (long)byi * 128, bn = (long)(bxi & 7) * 128;
  const int srow = l >> 2;
  const int scol = (l & 3) * 8;
  const u16* Ag0 = A + (bm + w * 32 + srow) * (long)K + scol;
  const u16* Ag1 = A + (bm + w * 32 + 16 + srow) * (long)K + scol;
  const u16* Bg0 = BT + (bn + w * 32 + srow) * (long)K + scol;
  const u16* Bg1 = BT + (bn + w * 32 + 16 + srow) * (long)K + scol;
  const int wo = w * 1024;
  f32x4 acc[4][4] = {};
  GLDS16(Ag0, &As[0][wo]);
  GLDS16(Ag1, &As[0][wo + 512]);
  GLDS16(Bg0, &Bs[0][wo]);
  GLDS16(Bg1, &Bs[0][wo + 512]);
  __syncthreads();
  int cur = 0;
  for (int k0 = 0; k0 < K; k0 += 32) {
    const int nxt = cur ^ 1;
    if (k0 + 32 < K) {
      GLDS16(Ag0 + k0 + 32, &As[nxt][wo]);
      GLDS16(Ag1 + k0 + 32, &As[nxt][wo + 512]);
      GLDS16(Bg0 + k0 + 32, &Bs[nxt][wo]);
      GLDS16(Bg1 + k0 + 32, &Bs[nxt][wo + 512]);
    }
    short8 af[4], bf[4];
#pragma unroll
    for (int i = 0; i < 4; i++)
      af[i] = *(const short8*)&As[cur][(wr + i * 16 + lr) * 32 + lg * 8];
#pragma unroll
    for (int i = 0; i < 4; i++)
      bf[i] = *(const short8*)&Bs[cur][(wc + i * 16 + lr) * 32 + lg * 8];
#pragma unroll
    for (int i = 0; i < 4; i++)
#pragma unroll
      for (int j = 0; j < 4; j++)
        acc[i][j] = MFMA_BF16(af[i], bf[j], acc[i][j], 0, 0, 0);
    __syncthreads();
    cur = nxt;
  }
#pragma unroll
  for (int i = 0; i < 4; i++)
#pragma unroll
    for (int j = 0; j < 4; j++) {
      long col = bn + wc + j * 16 + lr;
      float bvv = bias[col];
      if (sector == 2) {  // V -> VT layout: VT[(b*1024+col)*2048 + l]
        long row0 = bm + wr + i * 16 + lg * 4;
        long b = row0 >> 11, l0 = row0 & 2047;
        u16x4 ov;
#pragma unroll
        for (int r = 0; r < 4; r++) ov[r] = f2b(acc[i][j][r] + bvv);
        *(u16x4*)(Vo + (b * 1024 + col) * 2048 + l0) = ov;
      } else {
        u16* Out = sector == 0 ? Qo : Ko;
#pragma unroll
        for (int r = 0; r < 4; r++) {
          long row = bm + wr + i * 16 + lg * 4 + r;
          Out[row * 1024 + col] = f2b((acc[i][j][r] + bvv) * scale);
        }
      }
    }
}

// ------- 64x128x32 GEMM, 2-phase dbuf, HIGH OCCUPANCY (4 blocks/CU) -------
// Grid (8, 128) = 1024 blocks. 4 waves: wr=(w>>1)*32 (2 M-quadrants of 32),
// wc=(w&1)*64. acc[2][4]. LDS 24KB. OMODE: 1 = bf16 (+relu); 3 = fused-c2.
template <bool RELU, int OMODE>
__global__ __launch_bounds__(256, 4) void gemm_k(
    const u16* __restrict__ A, const u16* __restrict__ BT,
    const float* __restrict__ bias, u16* __restrict__ Cb,
    const float* __restrict__ w2, float* __restrict__ cvec, int M, int N,
    int K) {
  __shared__ u16 As[2][64 * 32];
  __shared__ u16 Bs[2][128 * 32];
  const int nwg = gridDim.x * gridDim.y;  // 1024, %8==0
  const int bid = blockIdx.x + blockIdx.y * gridDim.x;
  const int swz = (bid & 7) * (nwg >> 3) + (bid >> 3);
  const int bxi = swz % gridDim.x, byi = swz / gridDim.x;
  const int t = threadIdx.x;
  const int l = t & 63, w = t >> 6;
  const int lr = l & 15, lg = l >> 4;
  const int wr = (w >> 1) * 32, wc = (w & 1) * 64;
  const long bm = (long)byi * 64, bn = (long)bxi * 128;
  const int srow = l >> 2;         // 0..15
  const int scol = (l & 3) * 8;    // 0..24
  // wave w stages A rows [w*16, w*16+16) (1 gload), B rows [w*32,+32) (2)
  const u16* Ag0 = A + (bm + w * 16 + srow) * (long)K + scol;
  const u16* Bg0 = BT + (bn + w * 32 + srow) * (long)K + scol;
  const u16* Bg1 = BT + (bn + w * 32 + 16 + srow) * (long)K + scol;
  const int woA = w * 512;
  const int woB = w * 1024;
  f32x4 acc[2][4] = {};
  GLDS16(Ag0, &As[0][woA]);
  GLDS16(Bg0, &Bs[0][woB]);
  GLDS16(Bg1, &Bs[0][woB + 512]);
  __syncthreads();
  int cur = 0;
  for (int k0 = 0; k0 < K; k0 += 32) {
    const int nxt = cur ^ 1;
    if (k0 + 32 < K) {
      GLDS16(Ag0 + k0 + 32, &As[nxt][woA]);
      GLDS16(Bg0 + k0 + 32, &Bs[nxt][woB]);
      GLDS16(Bg1 + k0 + 32, &Bs[nxt][woB + 512]);
    }
    short8 af[2], bf[4];
#pragma unroll
    for (int i = 0; i < 2; i++)
      af[i] = *(const short8*)&As[cur][(wr + i * 16 + lr) * 32 + lg * 8];
#pragma unroll
    for (int j = 0; j < 4; j++)
      bf[j] = *(const short8*)&Bs[cur][(wc + j * 16 + lr) * 32 + lg * 8];
#pragma unroll
    for (int i = 0; i < 2; i++)
#pragma unroll
      for (int j = 0; j < 4; j++)
        acc[i][j] = MFMA_BF16(af[i], bf[j], acc[i][j], 0, 0, 0);
    __syncthreads();
    cur = nxt;
  }
  if (OMODE == 3) {
    float bvj[4], w2j[4];
#pragma unroll
    for (int j = 0; j < 4; j++) {
      long col = bn + wc + j * 16 + lr;
      bvj[j] = bias[col];
      w2j[j] = w2[col];
    }
#pragma unroll
    for (int i = 0; i < 2; i++)
#pragma unroll
      for (int r = 0; r < 4; r++) {
        float a2 = 0.f;
#pragma unroll
        for (int j = 0; j < 4; j++)
          a2 += fmaxf(acc[i][j][r] + bvj[j], 0.f) * w2j[j];
        a2 += __shfl_xor(a2, 1, 64);
        a2 += __shfl_xor(a2, 2, 64);
        a2 += __shfl_xor(a2, 4, 64);
        a2 += __shfl_xor(a2, 8, 64);
        if (lr == 0) {
          long row = bm + wr + i * 16 + lg * 4 + r;
          atomicAdd(&cvec[row], a2);
        }
      }
  } else {
#pragma unroll
    for (int i = 0; i < 2; i++)
#pragma unroll
      for (int j = 0; j < 4; j++) {
        long col = bn + wc + j * 16 + lr;
        float bv = bias[col];
#pragma unroll
        for (int r = 0; r < 4; r++) {
          long row = bm + wr + i * 16 + lg * 4 + r;
          float v2 = acc[i][j][r] + bv;
          if (RELU) v2 = fmaxf(v2, 0.f);
          Cb[row * N + col] = f2b(v2);
        }
      }
  }
}

// ---------------- flash attention v7c (R16, kept — at structure ceiling) ---
__global__ __launch_bounds__(256, 2) void flash_k(const u16* __restrict__ Q,
                                                  const u16* __restrict__ Kb,
                                                  const u16* __restrict__ VT,
                                                  u16* __restrict__ ctx) {
  __shared__ u16 Ks2[2][64 * 128];
  __shared__ u16 Vs2[2][128 * 64];
  const int nwg = gridDim.x * gridDim.y;
  const int bid = blockIdx.x + blockIdx.y * gridDim.x;
  const int swz = (bid & 7) * (nwg >> 3) + (bid >> 3);
  const int bxi = swz % gridDim.x, byi = swz / gridDim.x;
  const int t = threadIdx.x;
  const int l = t & 63, w = t >> 6;  // w in 0..3
  const int lr = l & 15, lg = l >> 4;
  const int b = byi >> 3, h = byi & 7;
  const long kbase = ((long)b * LL) * DD + h * DHH;
  const long vtbase = ((long)(b * 8 + h) * DHH) * LL;
  const int q0 = bxi * 128;

  short8 qf0[4], qf1[4];
  {
    const u16* qp0 = Q + kbase + (long)(q0 + w * 32 + lr) * DD + lg * 8;
    const u16* qp1 = qp0 + 16 * DD;
#pragma unroll
    for (int c = 0; c < 4; c++) {
      qf0[c] = *(const short8*)(qp0 + c * 32);
      qf1[c] = *(const short8*)(qp1 + c * 32);
    }
  }
  f32x4 oacc0[8] = {}, oacc1[8] = {};
  float mprev0 = -1e30f, mprev1 = -1e30f;
  float lsum0 = 0.f, lsum1 = 0.f;

  const u16* kg[4];
  const u16* vg[4];
  u16* kl[4];
  u16* vl[4];
#pragma unroll
  for (int i = 0; i < 4; i++) {
    int rk = w * 16 + 4 * i + (l >> 4);
    kg[i] = Kb + kbase + (long)rk * DD + ((l & 15) ^ (rk & 7)) * 8;
    kl[i] = &Ks2[0][(w * 16 + 4 * i) * 128];
    int rv = w * 32 + 8 * i + (l >> 3);
    vg[i] = VT + vtbase + (long)rv * LL + ((l & 7) ^ (rv & 7)) * 8;
    vl[i] = &Vs2[0][(w * 32 + 8 * i) * 64];
  }
#pragma unroll
  for (int i = 0; i < 4; i++) {
    GLDS16(kg[i], kl[i]);
    GLDS16(vg[i], vl[i]);
  }
  __syncthreads();

  int colk[4], colv[2];
#pragma unroll
  for (int c = 0; c < 4; c++) colk[c] = (((c * 4 + lg) ^ (lr & 7)) * 8);
#pragma unroll
  for (int kk = 0; kk < 2; kk++) colv[kk] = (((kk * 4 + lg) ^ (lr & 7)) * 8);

  const int NT = LL / 64;
  for (int it = 0; it < NT; ++it) {
    const int cur = it & 1;
    if (it + 1 < NT) {
      const int ko = (cur ^ 1) * (64 * 128);
      const int vo = (cur ^ 1) * (128 * 64);
#pragma unroll
      for (int i = 0; i < 4; i++) {
        kg[i] += 64 * DD;
        vg[i] += 64;
        GLDS16(kg[i], kl[i] + ko);
        GLDS16(vg[i], vl[i] + vo);
      }
    }
    const u16* Kc = &Ks2[cur][0];
    const u16* Vc = &Vs2[cur][0];

    f32x4 s0[4] = {}, s1[4] = {};
    __builtin_amdgcn_s_setprio(1);
#pragma unroll
    for (int jc = 0; jc < 4; jc++)
#pragma unroll
      for (int c = 0; c < 4; c++) {
        short8 kf = *(const short8*)&Kc[(jc * 16 + lr) * 128 + colk[c]];
        s0[jc] = MFMA_BF16(kf, qf0[c], s0[jc], 0, 0, 0);
        s1[jc] = MFMA_BF16(kf, qf1[c], s1[jc], 0, 0, 0);
      }
    __builtin_amdgcn_s_setprio(0);

    float mx0 = fmaxf(fmaxf(s0[0][0], s0[0][1]), fmaxf(s0[0][2], s0[0][3]));
    float mx1 = fmaxf(fmaxf(s1[0][0], s1[0][1]), fmaxf(s1[0][2], s1[0][3]));
#pragma unroll
    for (int jc = 1; jc < 4; jc++) {
      mx0 = fmaxf(mx0, fmaxf(fmaxf(s0[jc][0], s0[jc][1]),
                             fmaxf(s0[jc][2], s0[jc][3])));
      mx1 = fmaxf(mx1, fmaxf(fmaxf(s1[jc][0], s1[jc][1]),
                             fmaxf(s1[jc][2], s1[jc][3])));
    }
    mx0 = fmaxf(mx0, __shfl_xor(mx0, 16, 64));
    mx0 = fmaxf(mx0, __shfl_xor(mx0, 32, 64));
    mx1 = fmaxf(mx1, __shfl_xor(mx1, 16, 64));
    mx1 = fmaxf(mx1, __shfl_xor(mx1, 32, 64));

    if (__any((int)((mx0 > mprev0 + 8.f) || (mx1 > mprev1 + 8.f)))) {
      float mn0 = fmaxf(mprev0, mx0), mn1 = fmaxf(mprev1, mx1);
      float al0 = exp2_fast(mprev0 - mn0), al1 = exp2_fast(mprev1 - mn1);
      mprev0 = mn0;
      mprev1 = mn1;
      lsum0 *= al0;
      lsum1 *= al1;
      float ar0[4], ar1[4];
#pragma unroll
      for (int r = 0; r < 4; r++) {
        ar0[r] = __shfl(al0, lg * 4 + r, 64);
        ar1[r] = __shfl(al1, lg * 4 + r, 64);
      }
#pragma unroll
      for (int d8 = 0; d8 < 8; d8++)
#pragma unroll
        for (int r = 0; r < 4; r++) {
          oacc0[d8][r] *= ar0[r];
          oacc1[d8][r] *= ar1[r];
        }
    }

    u32 pk0[4][2], pk1[4][2];
    float la0 = 0.f, la1 = 0.f;
#pragma unroll
    for (int jc = 0; jc < 4; jc++) {
      float a0 = exp2_fast(s0[jc][0] - mprev0);
      float a1 = exp2_fast(s0[jc][1] - mprev0);
      float a2 = exp2_fast(s0[jc][2] - mprev0);
      float a3 = exp2_fast(s0[jc][3] - mprev0);
      la0 += (a0 + a1) + (a2 + a3);
      pk0[jc][0] = packbf(a0, a1);
      pk0[jc][1] = packbf(a2, a3);
      float b0 = exp2_fast(s1[jc][0] - mprev1);
      float b1 = exp2_fast(s1[jc][1] - mprev1);
      float b2 = exp2_fast(s1[jc][2] - mprev1);
      float b3 = exp2_fast(s1[jc][3] - mprev1);
      la1 += (b0 + b1) + (b2 + b3);
      pk1[jc][0] = packbf(b0, b1);
      pk1[jc][1] = packbf(b2, b3);
    }
    lsum0 += la0;
    lsum1 += la1;

    short8 pf0[2], pf1[2];
#pragma unroll
    for (int kk = 0; kk < 2; kk++) {
      u32x4 av0, av1;
#pragma unroll
      for (int m = 0; m < 4; m++) {
        int srcl = lr + ((((lg & 1) << 1) + (m >> 1)) << 4);
        u32 x0 = bperm(srcl, pk0[2 * kk][m & 1]);
        u32 x1 = bperm(srcl, pk0[2 * kk + 1][m & 1]);
        av0[m] = (lg >> 1) ? x1 : x0;
        u32 y0 = bperm(srcl, pk1[2 * kk][m & 1]);
        u32 y1 = bperm(srcl, pk1[2 * kk + 1][m & 1]);
        av1[m] = (lg >> 1) ? y1 : y0;
      }
      pf0[kk] = __builtin_bit_cast(short8, av0);
      pf1[kk] = __builtin_bit_cast(short8, av1);
    }

    __builtin_amdgcn_s_setprio(1);
#pragma unroll
    for (int kk = 0; kk < 2; kk++)
#pragma unroll
      for (int d8 = 0; d8 < 8; d8++) {
        short8 vf = *(const short8*)&Vc[(d8 * 16 + lr) * 64 + colv[kk]];
        oacc0[d8] = MFMA_BF16(pf0[kk], vf, oacc0[d8], 0, 0, 0);
        oacc1[d8] = MFMA_BF16(pf1[kk], vf, oacc1[d8], 0, 0, 0);
      }
    __builtin_amdgcn_s_setprio(0);
    __syncthreads();
  }

  lsum0 += __shfl_xor(lsum0, 16, 64);
  lsum0 += __shfl_xor(lsum0, 32, 64);
  lsum1 += __shfl_xor(lsum1, 16, 64);
  lsum1 += __shfl_xor(lsum1, 32, 64);
#pragma unroll
  for (int r = 0; r < 4; r++) {
    float inv0 = 1.f / __shfl(lsum0, lg * 4 + r, 64);
    float inv1 = 1.f / __shfl(lsum1, lg * 4 + r, 64);
    u16* cp0 = ctx + kbase + (long)(q0 + w * 32 + lg * 4 + r) * DD;
    u16* cp1 = cp0 + 16 * DD;
#pragma unroll
    for (int d8 = 0; d8 < 8; d8++) {
      cp0[d8 * 16 + lr] = f2b(oacc0[d8][r] * inv0);
      cp1[d8 * 16 + lr] = f2b(oacc1[d8][r] * inv1);
    }
  }
}

// ---------------- residual + layernorm --------------------------------
template <bool XB, bool RB>
__global__ __launch_bounds__(256) void ln_k(const void* __restrict__ Xp,
                                            const void* __restrict__ Rp,
                                            const float* __restrict__ gamma,
                                            const float* __restrict__ beta,
                                            u16* __restrict__ Hb) {
  const int row = blockIdx.x, t = threadIdx.x;
  const long off = (long)row * DD + t * 4;
  f32x4 v;
  if (XB) {
    u16x4 xv = *(const u16x4*)((const u16*)Xp + off);
#pragma unroll
    for (int i = 0; i < 4; i++) v[i] = b2f(xv[i]);
  } else {
    v = *(const f32x4*)((const float*)Xp + off);
  }
  if (RB) {
    u16x4 rv = *(const u16x4*)((const u16*)Rp + off);
#pragma unroll
    for (int i = 0; i < 4; i++) v[i] += b2f(rv[i]);
  } else {
    f32x4 rv = *(const f32x4*)((const float*)Rp + off);
#pragma unroll
    for (int i = 0; i < 4; i++) v[i] += rv[i];
  }
  float s = v[0] + v[1] + v[2] + v[3];
  float q = v[0] * v[0] + v[1] * v[1] + v[2] * v[2] + v[3] * v[3];
#pragma unroll
  for (int m = 32; m >= 1; m >>= 1) {
    s += __shfl_xor(s, m, 64);
    q += __shfl_xor(q, m, 64);
  }
  __shared__ float red[8];
  if ((t & 63) == 0) {
    red[t >> 6] = s;
    red[4 + (t >> 6)] = q;
  }
  __syncthreads();
  s = red[0] + red[1] + red[2] + red[3];
  q = red[4] + red[5] + red[6] + red[7];
  const float mean = s * (1.f / 1024.f);
  const float var = q * (1.f / 1024.f) - mean * mean;
  const float rstd = rsqrtf(var + 1e-12f);
  f32x4 g = *(const f32x4*)(gamma + t * 4);
  f32x4 be = *(const f32x4*)(beta + t * 4);
  u16x4 ob;
#pragma unroll
  for (int i = 0; i < 4; i++)
    ob[i] = f2b(g[i] * (v[i] - mean) * rstd + be[i]);
  *(u16x4*)(Hb + off) = ob;
}

// ---------------- small [4,Lr]@[Lr,N] GEMM: split-K partials + reduce -----
template <bool BR>
__global__ __launch_bounds__(256) void smm_part(const float* __restrict__ Cin,
                                                const float* __restrict__ W,
                                                float* __restrict__ P, int Lr,
                                                int N, int SL,
                                                const float* __restrict__ b0) {
  const int j = blockIdx.x * 256 + threadIdx.x;
  const int l0 = blockIdx.y * SL;
  const float bb = BR ? b0[0] : 0.f;
  float a0 = 0, a1 = 0, a2 = 0, a3 = 0;
  for (int ll = l0; ll < l0 + SL; ll++) {
    float wv = W[(long)ll * N + j];
    float c0 = Cin[ll], c1 = Cin[Lr + ll], c2 = Cin[2 * Lr + ll],
          c3 = Cin[3 * Lr + ll];
    if (BR) {
      c0 = fmaxf(c0 + bb, 0.f);
      c1 = fmaxf(c1 + bb, 0.f);
      c2 = fmaxf(c2 + bb, 0.f);
      c3 = fmaxf(c3 + bb, 0.f);
    }
    a0 += c0 * wv;
    a1 += c1 * wv;
    a2 += c2 * wv;
    a3 += c3 * wv;
  }
  float* Pp = P + ((long)blockIdx.y * 4) * N + j;
  Pp[0] = a0;
  Pp[N] = a1;
  Pp[2 * N] = a2;
  Pp[3 * N] = a3;
}

template <bool RELU>
__global__ __launch_bounds__(256) void smm_red(const float* __restrict__ P,
                                               const float* __restrict__ bias,
                                               float* __restrict__ Out, int N,
                                               int S) {
  const int j = blockIdx.x * 256 + threadIdx.x;
#pragma unroll
  for (int b = 0; b < 4; b++) {
    float a = 0;
    for (int s = 0; s < S; s++) a += P[((long)s * 4 + b) * N + j];
    a += bias[j];
    if (RELU) a = fmaxf(a, 0.f);
    Out[(long)b * N + j] = a;
  }
}

extern "C" void kernel_launch(void* const* d_in, const int* in_sizes, int n_in,
                              void* d_out, int out_size, void* d_ws,
                              size_t ws_size, hipStream_t stream) {
  (void)in_sizes; (void)n_in; (void)out_size; (void)ws_size;
  const float* x = (const float*)d_in[0];
  const float* wq = (const float*)d_in[1];
  const float* bq = (const float*)d_in[2];
  const float* wk = (const float*)d_in[3];
  const float* bk = (const float*)d_in[4];
  const float* wv = (const float*)d_in[5];
  const float* bv = (const float*)d_in[6];
  const float* gamma = (const float*)d_in[7];
  const float* beta = (const float*)d_in[8];
  const float* wff = (const float*)d_in[9];
  const float* bff = (const float*)d_in[10];
  const float* wc1 = (const float*)d_in[11];
  const float* bc1 = (const float*)d_in[12];
  const float* wc2 = (const float*)d_in[13];
  const float* bc2 = (const float*)d_in[14];
  const float* wl1 = (const float*)d_in[15];
  const float* bl1 = (const float*)d_in[16];
  const float* wl2 = (const float*)d_in[17];
  const float* bl2 = (const float*)d_in[18];

  char* wsp = (char*)d_ws;
  size_t off = 0;
  auto take = [&](size_t bytes) -> char* {
    char* p = wsp + off;
    off += (bytes + 255) & ~(size_t)255;
    return p;
  };
  u16* xb = (u16*)take((size_t)8192 * 1024 * 2);
  u16* wqT = (u16*)take((size_t)1024 * 1024 * 2);
  u16* wkT = (u16*)take((size_t)1024 * 1024 * 2);
  u16* wvT = (u16*)take((size_t)1024 * 1024 * 2);
  u16* wffT = (u16*)take((size_t)1024 * 1024 * 2);
  u16* wc1T = (u16*)take((size_t)1024 * 1024 * 2);
  u16* qb = (u16*)take((size_t)8192 * 1024 * 2);
  u16* kbuf = (u16*)take((size_t)8192 * 1024 * 2);
  u16* vT = (u16*)take((size_t)8192 * 1024 * 2);
  u16* ctxb = (u16*)take((size_t)8192 * 1024 * 2);
  u16* h1b = (u16*)take((size_t)8192 * 1024 * 2);
  u16* ffb = (u16*)take((size_t)8192 * 1024 * 2);
  float* cvec = (float*)take(8192 * 4);
  float* c3 = (float*)take(8192 * 4);
  float* P1 = (float*)take((size_t)16 * 4 * 2048 * 4);
  float* P2 = (float*)take((size_t)16 * 4 * 256 * 4);
  u16* h2b = qb;  // dead after flash

  cvt_k<<<8192, 256, 0, stream>>>(x, xb, (long)8192 * 1024);
  tr5_k<<<dim3(32, 32, 5), 256, 0, stream>>>(wq, wk, wv, wff, wc1, wqT, wkT,
                                             wvT, wffT, wc1T);

  // fused QKV: grid (3*8, 64); Q scale folds 1/sqrt(128)*log2(e)
  qkv_k<<<dim3(24, 64), 256, 0, stream>>>(xb, wqT, wkT, wvT, bq, bk, bv,
                                          0.12751743f, qb, kbuf, vT);
  flash_k<<<dim3(16, 32), 256, 0, stream>>>(qb, kbuf, vT, ctxb);
  // LN1: xb (bf16) + ctx (bf16) -> h1b (bf16)
  ln_k<true, true><<<8192, 256, 0, stream>>>(xb, ctxb, gamma, beta, h1b);
  // ff GEMM: 64x128 tile, 1024 blocks = 4/CU
  dim3 gg(8, 128);
  gemm_k<true, 1><<<gg, 256, 0, stream>>>(h1b, wffT, bff, ffb, nullptr,
                                          nullptr, 8192, 1024, 1024);
  // LN2: h1b (bf16) + ff (bf16) -> h2b
  ln_k<true, true><<<8192, 256, 0, stream>>>(h1b, ffb, gamma, beta, h2b);
  hipMemsetAsync(cvec, 0, 8192 * sizeof(float), stream);
  gemm_k<true, 3><<<gg, 256, 0, stream>>>(h2b, wc1T, bc1, nullptr, wc2, cvec,
                                          8192, 1024, 1024);
  smm_part<true><<<dim3(8, 16), 256, 0, stream>>>(cvec, wl1, P1, 2048, 2048,
                                                  128, bc2);
  smm_red<true><<<8, 256, 0, stream>>>(P1, bl1, c3, 2048, 16);
  smm_part<false><<<dim3(1, 16), 256, 0, stream>>>(c3, wl2, P2, 2048, 256,
                                                   128, nullptr);
  smm_red<false><<<1, 256, 0, stream>>>(P2, bl2, (float*)d_out, 256, 16);
}